// Round 1
// baseline (14649.034 us; speedup 1.0000x reference)
//
#include <hip/hip_runtime.h>
#include <cstdint>

typedef float f32x4 __attribute__((ext_vector_type(4)));
typedef __bf16 bf16x8 __attribute__((ext_vector_type(8)));
typedef unsigned short ushort8 __attribute__((ext_vector_type(8)));
typedef unsigned short u16;
typedef unsigned int u32;

// ---------- helpers ----------
__device__ __forceinline__ u16 f2bf(float f) {
  u32 u = __builtin_bit_cast(u32, f);
  u32 r = (u + 0x7fffu + ((u >> 16) & 1u)) >> 16;
  return (u16)r;
}

__device__ __forceinline__ void gload_lds16(const void* g, void* lds) {
  __builtin_amdgcn_global_load_lds(
      (const __attribute__((address_space(1))) u32*)g,
      (__attribute__((address_space(3))) u32*)lds,
      16, 0, 0);
}

// ---------- one-time: cast + transpose weights to bf16 ----------
// w1t: [5][512][256]  (w1t[l][n][k] = W1[l][k][n])
// w2t: [5][256][512]  (w2t[l][n][k] = W2[l][k][n])
__global__ __launch_bounds__(256) void k_cast_weights(
    const float* __restrict__ W1, const float* __restrict__ W2,
    u16* __restrict__ w1t, u16* __restrict__ w2t) {
  const int PER = 5 * 512 * 256;
  int idx = blockIdx.x * 256 + threadIdx.x;
  if (idx < PER) {
    int l = idx / (512 * 256);
    int rem = idx % (512 * 256);
    int n = rem / 256, k = rem % 256;
    w1t[idx] = f2bf(W1[l * 131072 + k * 512 + n]);
  } else if (idx < 2 * PER) {
    int j = idx - PER;
    int l = j / (256 * 512);
    int rem = j % (256 * 512);
    int n = rem / 512, k = rem % 512;
    w2t[j] = f2bf(W2[l * 131072 + k * 256 + n]);
  }
}

// ---------- node input embedding: h = x_emb1[atom] + x_emb2[chir] ----------
__global__ __launch_bounds__(256) void k_node_init(
    const int* __restrict__ xa, const int* __restrict__ xc,
    const float* __restrict__ e1, const float* __restrict__ e2,
    float* __restrict__ h, int N) {
  int idx = blockIdx.x * 256 + threadIdx.x;  // N*64 threads, 4 ch each
  if (idx >= N * 64) return;
  int node = idx >> 6, c = (idx & 63) * 4;
  int a = xa[node], ch = xc[node];
  float4 v1 = *(const float4*)&e1[a * 256 + c];
  float4 v2 = *(const float4*)&e2[ch * 256 + c];
  float4 o = make_float4(v1.x + v2.x, v1.y + v2.y, v1.z + v2.z, v1.w + v2.w);
  *(float4*)&h[(size_t)node * 256 + c] = o;
}

// ---------- self-loop: agg = h + ee(4,0)  (also initializes agg) ----------
__global__ __launch_bounds__(256) void k_self_init(
    const float* __restrict__ h, const float* __restrict__ ee1s,
    const float* __restrict__ ee2s, float* __restrict__ agg, int N) {
  int idx = blockIdx.x * 256 + threadIdx.x;
  if (idx >= N * 64) return;
  int c = (idx & 63) * 4;
  float4 hv = *(const float4*)&h[(size_t)idx * 4];
  float4 a = *(const float4*)&ee1s[c];
  float4 b = *(const float4*)&ee2s[c];
  float4 o = make_float4(hv.x + a.x + b.x, hv.y + a.y + b.y,
                         hv.z + a.z + b.z, hv.w + a.w + b.w);
  *(float4*)&agg[(size_t)idx * 4] = o;
}

// ---------- edge scatter: agg[dst] += h[src] + ee1[et] + ee2[ed] ----------
__global__ __launch_bounds__(256) void k_scatter(
    const float* __restrict__ h, const int* __restrict__ src,
    const int* __restrict__ dst, const int* __restrict__ et,
    const int* __restrict__ ed, const float* __restrict__ ee1,
    const float* __restrict__ ee2, float* __restrict__ agg, int E) {
  int e = blockIdx.x * 4 + (threadIdx.x >> 6);
  if (e >= E) return;
  int lane = threadIdx.x & 63;
  int s = src[e], d = dst[e];
  int t = et[e], r = ed[e];
  int c = lane * 4;
  float4 hv = *(const float4*)&h[(size_t)s * 256 + c];
  float4 a = *(const float4*)&ee1[t * 256 + c];
  float4 b = *(const float4*)&ee2[r * 256 + c];
  float* p = &agg[(size_t)d * 256 + c];
  unsafeAtomicAdd(p + 0, hv.x + a.x + b.x);
  unsafeAtomicAdd(p + 1, hv.y + a.y + b.y);
  unsafeAtomicAdd(p + 2, hv.z + a.z + b.z);
  unsafeAtomicAdd(p + 3, hv.w + a.w + b.w);
}

// ---------- f32 -> bf16 cast (8 elems/thread) ----------
__global__ __launch_bounds__(256) void k_cast_bf16(
    const float* __restrict__ in, u16* __restrict__ out, long n) {
  long i = ((long)blockIdx.x * 256 + threadIdx.x) * 8;
  if (i >= n) return;
  float4 a = *(const float4*)&in[i];
  float4 b = *(const float4*)&in[i + 4];
  ushort8 o;
  o[0] = f2bf(a.x); o[1] = f2bf(a.y); o[2] = f2bf(a.z); o[3] = f2bf(a.w);
  o[4] = f2bf(b.x); o[5] = f2bf(b.y); o[6] = f2bf(b.z); o[7] = f2bf(b.w);
  *(ushort8*)&out[i] = o;
}

// ---------- MFMA GEMM: C[M,NC] = A[M,K] @ B[K,NC], B given transposed Bt[NC,K]
// 128x128 block tile, 4 waves (2x2), each wave 64x64 (4x4 frags of 16x16),
// BK=32, global_load_lds staging, optional fused bias+relu+bf16 output.
template <int K, int NC, bool RELU_BF16>
__global__ __launch_bounds__(256) void k_gemm(
    const u16* __restrict__ A, const u16* __restrict__ Bt,
    const float* __restrict__ bias, void* __restrict__ outp, int M) {
  __shared__ u16 As[128 * 32];
  __shared__ u16 Bs[128 * 32];
  const int tid = threadIdx.x;
  const int lane = tid & 63;
  const int wv = tid >> 6;
  const int wrow = wv >> 1, wcol = wv & 1;
  const int m0 = blockIdx.x * 128;
  const int n0 = blockIdx.y * 128;
  const int fr = lane & 15;
  const int kg = (lane >> 4) * 8;

  f32x4 acc[4][4];
#pragma unroll
  for (int m = 0; m < 4; ++m)
#pragma unroll
    for (int n = 0; n < 4; ++n) acc[m][n] = (f32x4){0.f, 0.f, 0.f, 0.f};

  for (int k0 = 0; k0 < K; k0 += 32) {
    __syncthreads();
#pragma unroll
    for (int j = 0; j < 2; ++j) {
      const int chunk = j * 256 + tid;
      int ar = m0 + (chunk >> 2);
      if (ar >= M) ar = M - 1;  // clamp tail rows (stores are predicated)
      const u16* ga = A + (size_t)ar * K + k0 + (chunk & 3) * 8;
      gload_lds16(ga, As + (size_t)(j * 256 + (tid & ~63)) * 8);
      const int br = n0 + (chunk >> 2);
      const u16* gb = Bt + (size_t)br * K + k0 + (chunk & 3) * 8;
      gload_lds16(gb, Bs + (size_t)(j * 256 + (tid & ~63)) * 8);
    }
    __syncthreads();  // compiler emits vmcnt(0) drain before barrier
    bf16x8 af[4], bfr[4];
#pragma unroll
    for (int m = 0; m < 4; ++m)
      af[m] = *(const bf16x8*)&As[(wrow * 64 + m * 16 + fr) * 32 + kg];
#pragma unroll
    for (int n = 0; n < 4; ++n)
      bfr[n] = *(const bf16x8*)&Bs[(wcol * 64 + n * 16 + fr) * 32 + kg];
#pragma unroll
    for (int m = 0; m < 4; ++m)
#pragma unroll
      for (int n = 0; n < 4; ++n)
        acc[m][n] = __builtin_amdgcn_mfma_f32_16x16x32_bf16(af[m], bfr[n],
                                                            acc[m][n], 0, 0, 0);
  }

  const int rb = (lane >> 4) * 4;
#pragma unroll
  for (int m = 0; m < 4; ++m) {
#pragma unroll
    for (int n = 0; n < 4; ++n) {
      const int col = n0 + wcol * 64 + n * 16 + fr;
      const float bv = bias[col];
#pragma unroll
      for (int j = 0; j < 4; ++j) {
        const int row = m0 + wrow * 64 + m * 16 + rb + j;
        if (row < M) {
          float v = acc[m][n][j] + bv;
          if (RELU_BF16) {
            v = fmaxf(v, 0.f);
            ((u16*)outp)[(size_t)row * NC + col] = f2bf(v);
          } else {
            ((float*)outp)[(size_t)row * NC + col] = v;
          }
        }
      }
    }
  }
}

// ---------- BN stats: per-channel sum / sumsq ----------
__global__ __launch_bounds__(256) void k_bn_stats(
    const float* __restrict__ hl, float* __restrict__ stats, int N) {
  int c = threadIdx.x;  // 256 channels
  float s = 0.f, s2 = 0.f;
  for (int r = blockIdx.x; r < N; r += gridDim.x) {
    float v = hl[(size_t)r * 256 + c];
    s += v;
    s2 += v * v;
  }
  unsafeAtomicAdd(&stats[c], s);
  unsafeAtomicAdd(&stats[256 + c], s2);
}

__global__ __launch_bounds__(256) void k_bn_finalize(
    float* __restrict__ stats, const float* __restrict__ gamma,
    const float* __restrict__ beta, int l, float invN) {
  int c = threadIdx.x;
  float mean = stats[c] * invN;
  float var = stats[256 + c] * invN - mean * mean;
  float sc = gamma[l * 256 + c] * rsqrtf(var + 1e-5f);
  stats[512 + c] = sc;
  stats[768 + c] = beta[l * 256 + c] - mean * sc;
}

template <bool RELU>
__global__ __launch_bounds__(256) void k_bn_apply(
    const float* __restrict__ hl, const float* __restrict__ stats,
    float* __restrict__ out, int N) {
  int idx = blockIdx.x * 256 + threadIdx.x;  // N*64 threads
  if (idx >= N * 64) return;
  int c = (idx & 63) * 4;
  float4 v = *(const float4*)&hl[(size_t)idx * 4];
  float4 sc = *(const float4*)&stats[512 + c];
  float4 sh = *(const float4*)&stats[768 + c];
  float4 o = make_float4(v.x * sc.x + sh.x, v.y * sc.y + sh.y,
                         v.z * sc.z + sh.z, v.w * sc.w + sh.w);
  if (RELU) {
    o.x = fmaxf(o.x, 0.f); o.y = fmaxf(o.y, 0.f);
    o.z = fmaxf(o.z, 0.f); o.w = fmaxf(o.w, 0.f);
  }
  *(float4*)&out[(size_t)idx * 4] = o;
}

// ---------- launch ----------
extern "C" void kernel_launch(void* const* d_in, const int* in_sizes, int n_in,
                              void* d_out, int out_size, void* d_ws,
                              size_t ws_size, hipStream_t stream) {
  const int* x_atom = (const int*)d_in[0];
  const int* x_chir = (const int*)d_in[1];
  const int* esrc = (const int*)d_in[2];
  const int* edst = (const int*)d_in[3];
  const int* etype = (const int*)d_in[4];
  const int* edir = (const int*)d_in[5];
  const float* x_emb1 = (const float*)d_in[6];
  const float* x_emb2 = (const float*)d_in[7];
  const float* eemb1 = (const float*)d_in[8];
  const float* eemb2 = (const float*)d_in[9];
  const float* W1 = (const float*)d_in[10];
  const float* b1 = (const float*)d_in[11];
  const float* W2 = (const float*)d_in[12];
  const float* b2 = (const float*)d_in[13];
  const float* gamma = (const float*)d_in[14];
  const float* beta = (const float*)d_in[15];

  const int N = in_sizes[0];
  const int E = in_sizes[2];

  // ws layout (aliased on purpose):
  //   buf0: h (f32, N*256)  -> inter (bf16, N*512, same bytes) -> next h
  //   buf1: agg (f32)       -> hl (GEMM2 out, f32)
  //   buf2: aggb (bf16)
  char* ws = (char*)d_ws;
  size_t off = 0;
  float* h = (float*)(ws + off); off += (size_t)N * 256 * 4;
  float* agg = (float*)(ws + off); off += (size_t)N * 256 * 4;
  u16* aggb = (u16*)(ws + off); off += (size_t)N * 256 * 2;
  u16* w1t = (u16*)(ws + off); off += (size_t)5 * 512 * 256 * 2;
  u16* w2t = (u16*)(ws + off); off += (size_t)5 * 256 * 512 * 2;
  float* stats = (float*)(ws + off); off += 4096;
  u16* interb = (u16*)h;   // aliases buf0 (h is dead once inter is written)
  float* hl = agg;         // aliases buf1 (agg is dead once cast to bf16)

  const int gN64 = (N * 64 + 255) / 256;
  const int gMB = (N + 127) / 128;  // GEMM row-blocks (782)

  k_cast_weights<<<(2 * 5 * 512 * 256 + 255) / 256, 256, 0, stream>>>(W1, W2,
                                                                      w1t, w2t);
  k_node_init<<<gN64, 256, 0, stream>>>(x_atom, x_chir, x_emb1, x_emb2, h, N);

  for (int l = 0; l < 5; ++l) {
    const float* ee1 = eemb1 + (size_t)l * 6 * 256;
    const float* ee2 = eemb2 + (size_t)l * 3 * 256;
    k_self_init<<<gN64, 256, 0, stream>>>(h, ee1 + 4 * 256, ee2, agg, N);
    k_scatter<<<(E + 3) / 4, 256, 0, stream>>>(h, esrc, edst, etype, edir, ee1,
                                               ee2, agg, E);
    k_cast_bf16<<<(N * 32 + 255) / 256, 256, 0, stream>>>(agg, aggb,
                                                          (long)N * 256);
    k_gemm<256, 512, true><<<dim3(gMB, 4), 256, 0, stream>>>(
        aggb, w1t + (size_t)l * 512 * 256, b1 + l * 512, interb, N);
    k_gemm<512, 256, false><<<dim3(gMB, 2), 256, 0, stream>>>(
        interb, w2t + (size_t)l * 256 * 512, b2 + l * 256, hl, N);
    hipMemsetAsync(stats, 0, 2048, stream);
    k_bn_stats<<<1024, 256, 0, stream>>>(hl, stats, N);
    k_bn_finalize<<<1, 256, 0, stream>>>(stats, gamma, beta, l, 1.f / N);
    if (l < 4)
      k_bn_apply<true><<<gN64, 256, 0, stream>>>(hl, stats, h, N);
    else
      k_bn_apply<false><<<gN64, 256, 0, stream>>>(hl, stats, (float*)d_out, N);
  }
}

// Round 3
// 1991.417 us; speedup vs baseline: 7.3561x; 7.3561x over previous
//
#include <hip/hip_runtime.h>
#include <cstdint>

typedef float f32x4 __attribute__((ext_vector_type(4)));
typedef __bf16 bf16x8 __attribute__((ext_vector_type(8)));
typedef unsigned short ushort8 __attribute__((ext_vector_type(8)));
typedef unsigned short ushort4v __attribute__((ext_vector_type(4)));
typedef unsigned short u16;
typedef unsigned int u32;

// ---------- helpers ----------
__device__ __forceinline__ u16 f2bf(float f) {
  u32 u = __builtin_bit_cast(u32, f);
  u32 r = (u + 0x7fffu + ((u >> 16) & 1u)) >> 16;
  return (u16)r;
}

__device__ __forceinline__ void gload_lds16(const void* g, void* lds) {
  __builtin_amdgcn_global_load_lds(
      (const __attribute__((address_space(1))) u32*)g,
      (__attribute__((address_space(3))) u32*)lds,
      16, 0, 0);
}

// ---------- one-time: cast + transpose weights to bf16 ----------
__global__ __launch_bounds__(256) void k_cast_weights(
    const float* __restrict__ W1, const float* __restrict__ W2,
    u16* __restrict__ w1t, u16* __restrict__ w2t) {
  const int PER = 5 * 512 * 256;
  int idx = blockIdx.x * 256 + threadIdx.x;
  if (idx < PER) {
    int l = idx / (512 * 256);
    int rem = idx % (512 * 256);
    int n = rem / 256, k = rem % 256;
    w1t[idx] = f2bf(W1[l * 131072 + k * 512 + n]);
  } else if (idx < 2 * PER) {
    int j = idx - PER;
    int l = j / (256 * 512);
    int rem = j % (256 * 512);
    int n = rem / 512, k = rem % 512;
    w2t[j] = f2bf(W2[l * 131072 + k * 256 + n]);
  }
}

// ---------- node input embedding ----------
__global__ __launch_bounds__(256) void k_node_init(
    const int* __restrict__ xa, const int* __restrict__ xc,
    const float* __restrict__ e1, const float* __restrict__ e2,
    float* __restrict__ h, int N) {
  int idx = blockIdx.x * 256 + threadIdx.x;
  if (idx >= N * 64) return;
  int node = idx >> 6, c = (idx & 63) * 4;
  int a = xa[node], ch = xc[node];
  float4 v1 = *(const float4*)&e1[a * 256 + c];
  float4 v2 = *(const float4*)&e2[ch * 256 + c];
  float4 o = make_float4(v1.x + v2.x, v1.y + v2.y, v1.z + v2.z, v1.w + v2.w);
  *(float4*)&h[(size_t)node * 256 + c] = o;
}

// ---------- CSR build ----------
__global__ __launch_bounds__(256) void k_deg_count(
    const int* __restrict__ dst, int* __restrict__ deg, int E) {
  int e = blockIdx.x * 256 + threadIdx.x;
  if (e < E) atomicAdd(&deg[dst[e]], 1);
}

__global__ __launch_bounds__(256) void k_scan1(
    const int* __restrict__ deg, int* __restrict__ rp,
    int* __restrict__ bsum, int N) {
  __shared__ int s[256];
  int i = blockIdx.x * 256 + threadIdx.x;
  int v = (i < N) ? deg[i] : 0;
  s[threadIdx.x] = v;
  __syncthreads();
#pragma unroll
  for (int off = 1; off < 256; off <<= 1) {
    int t = (threadIdx.x >= off) ? s[threadIdx.x - off] : 0;
    __syncthreads();
    s[threadIdx.x] += t;
    __syncthreads();
  }
  if (i < N) rp[i] = s[threadIdx.x] - v;
  if (threadIdx.x == 255) bsum[blockIdx.x] = s[255];
}

__global__ __launch_bounds__(512) void k_scan2(
    const int* __restrict__ bsum, int* __restrict__ bexcl, int B) {
  __shared__ int s[512];
  int v = (threadIdx.x < B) ? bsum[threadIdx.x] : 0;
  s[threadIdx.x] = v;
  __syncthreads();
#pragma unroll
  for (int off = 1; off < 512; off <<= 1) {
    int t = (threadIdx.x >= off) ? s[threadIdx.x - off] : 0;
    __syncthreads();
    s[threadIdx.x] += t;
    __syncthreads();
  }
  if (threadIdx.x < B) bexcl[threadIdx.x] = s[threadIdx.x] - v;
}

__global__ __launch_bounds__(256) void k_scan3(
    int* __restrict__ rp, const int* __restrict__ bexcl,
    int* __restrict__ cur, int N, int E) {
  int i = blockIdx.x * 256 + threadIdx.x;
  if (i < N) {
    int v = rp[i] + bexcl[blockIdx.x];
    rp[i] = v;
    cur[i] = v;
  }
  if (i == 0) rp[N] = E;
}

__global__ __launch_bounds__(256) void k_fill(
    const int* __restrict__ src, const int* __restrict__ dst,
    const int* __restrict__ et, const int* __restrict__ ed,
    int* __restrict__ cur, u32* __restrict__ adj, int E) {
  int e = blockIdx.x * 256 + threadIdx.x;
  if (e >= E) return;
  int pos = atomicAdd(&cur[dst[e]], 1);
  adj[pos] = (u32)src[e] | ((u32)et[e] << 17) | ((u32)ed[e] << 20);
}

// ---------- gather-aggregate: agg[n] = h[n]+ee_self + sum_in (h[src]+ee) ----
__global__ __launch_bounds__(256) void k_gather(
    const float* __restrict__ h, const int* __restrict__ rp,
    const u32* __restrict__ adj, const float* __restrict__ ee1,
    const float* __restrict__ ee2, u16* __restrict__ aggb, int N) {
  int node = blockIdx.x * 4 + (threadIdx.x >> 6);
  if (node >= N) return;
  int lane = threadIdx.x & 63;
  int c = lane * 4;
  // self loop: edge attr [4, 0]
  float4 hv = *(const float4*)&h[(size_t)node * 256 + c];
  float4 e1v = *(const float4*)&ee1[4 * 256 + c];
  float4 e2v = *(const float4*)&ee2[c];
  float ax = hv.x + e1v.x + e2v.x, ay = hv.y + e1v.y + e2v.y;
  float az = hv.z + e1v.z + e2v.z, aw = hv.w + e1v.w + e2v.w;
  int beg = rp[node], end = rp[node + 1];
  for (int i = beg; i < end; ++i) {
    u32 p = adj[i];
    int s = p & 0x1FFFF;
    int t = (p >> 17) & 7;
    int r = (p >> 20) & 3;
    float4 sv = *(const float4*)&h[(size_t)s * 256 + c];
    float4 a = *(const float4*)&ee1[t * 256 + c];
    float4 b = *(const float4*)&ee2[r * 256 + c];
    ax += sv.x + a.x + b.x;
    ay += sv.y + a.y + b.y;
    az += sv.z + a.z + b.z;
    aw += sv.w + a.w + b.w;
  }
  ushort4v o;
  o[0] = f2bf(ax); o[1] = f2bf(ay); o[2] = f2bf(az); o[3] = f2bf(aw);
  *(ushort4v*)&aggb[(size_t)node * 256 + c] = o;
}

// ---------- MFMA GEMM ----------
template <int K, int NC, bool RELU_BF16>
__global__ __launch_bounds__(256) void k_gemm(
    const u16* __restrict__ A, const u16* __restrict__ Bt,
    const float* __restrict__ bias, void* __restrict__ outp, int M) {
  __shared__ u16 As[128 * 32];
  __shared__ u16 Bs[128 * 32];
  const int tid = threadIdx.x;
  const int lane = tid & 63;
  const int wv = tid >> 6;
  const int wrow = wv >> 1, wcol = wv & 1;
  const int m0 = blockIdx.x * 128;
  const int n0 = blockIdx.y * 128;
  const int fr = lane & 15;
  const int kg = (lane >> 4) * 8;

  f32x4 acc[4][4];
#pragma unroll
  for (int m = 0; m < 4; ++m)
#pragma unroll
    for (int n = 0; n < 4; ++n) acc[m][n] = (f32x4){0.f, 0.f, 0.f, 0.f};

  for (int k0 = 0; k0 < K; k0 += 32) {
    __syncthreads();
#pragma unroll
    for (int j = 0; j < 2; ++j) {
      const int chunk = j * 256 + tid;
      int ar = m0 + (chunk >> 2);
      if (ar >= M) ar = M - 1;
      const u16* ga = A + (size_t)ar * K + k0 + (chunk & 3) * 8;
      gload_lds16(ga, As + (size_t)(j * 256 + (tid & ~63)) * 8);
      const int br = n0 + (chunk >> 2);
      const u16* gb = Bt + (size_t)br * K + k0 + (chunk & 3) * 8;
      gload_lds16(gb, Bs + (size_t)(j * 256 + (tid & ~63)) * 8);
    }
    __syncthreads();
    bf16x8 af[4], bfr[4];
#pragma unroll
    for (int m = 0; m < 4; ++m)
      af[m] = *(const bf16x8*)&As[(wrow * 64 + m * 16 + fr) * 32 + kg];
#pragma unroll
    for (int n = 0; n < 4; ++n)
      bfr[n] = *(const bf16x8*)&Bs[(wcol * 64 + n * 16 + fr) * 32 + kg];
#pragma unroll
    for (int m = 0; m < 4; ++m)
#pragma unroll
      for (int n = 0; n < 4; ++n)
        acc[m][n] = __builtin_amdgcn_mfma_f32_16x16x32_bf16(af[m], bfr[n],
                                                            acc[m][n], 0, 0, 0);
  }

  const int rb = (lane >> 4) * 4;
#pragma unroll
  for (int m = 0; m < 4; ++m) {
#pragma unroll
    for (int n = 0; n < 4; ++n) {
      const int col = n0 + wcol * 64 + n * 16 + fr;
      const float bv = bias[col];
#pragma unroll
      for (int j = 0; j < 4; ++j) {
        const int row = m0 + wrow * 64 + m * 16 + rb + j;
        if (row < M) {
          float v = acc[m][n][j] + bv;
          if (RELU_BF16) {
            v = fmaxf(v, 0.f);
            ((u16*)outp)[(size_t)row * NC + col] = f2bf(v);
          } else {
            ((float*)outp)[(size_t)row * NC + col] = v;
          }
        }
      }
    }
  }
}

// ---------- BN ----------
__global__ __launch_bounds__(256) void k_bn_stats(
    const float* __restrict__ hl, float* __restrict__ stats, int N) {
  int c = threadIdx.x;
  float s = 0.f, s2 = 0.f;
  for (int r = blockIdx.x; r < N; r += gridDim.x) {
    float v = hl[(size_t)r * 256 + c];
    s += v;
    s2 += v * v;
  }
  unsafeAtomicAdd(&stats[c], s);
  unsafeAtomicAdd(&stats[256 + c], s2);
}

__global__ __launch_bounds__(256) void k_bn_finalize(
    float* __restrict__ stats, const float* __restrict__ gamma,
    const float* __restrict__ beta, int l, float invN) {
  int c = threadIdx.x;
  float mean = stats[c] * invN;
  float var = stats[256 + c] * invN - mean * mean;
  float sc = gamma[l * 256 + c] * rsqrtf(var + 1e-5f);
  stats[512 + c] = sc;
  stats[768 + c] = beta[l * 256 + c] - mean * sc;
}

template <bool RELU>
__global__ __launch_bounds__(256) void k_bn_apply(
    const float* __restrict__ hl, const float* __restrict__ stats,
    float* __restrict__ out, int N) {
  int idx = blockIdx.x * 256 + threadIdx.x;
  if (idx >= N * 64) return;
  int c = (idx & 63) * 4;
  float4 v = *(const float4*)&hl[(size_t)idx * 4];
  float4 sc = *(const float4*)&stats[512 + c];
  float4 sh = *(const float4*)&stats[768 + c];
  float4 o = make_float4(v.x * sc.x + sh.x, v.y * sc.y + sh.y,
                         v.z * sc.z + sh.z, v.w * sc.w + sh.w);
  if (RELU) {
    o.x = fmaxf(o.x, 0.f); o.y = fmaxf(o.y, 0.f);
    o.z = fmaxf(o.z, 0.f); o.w = fmaxf(o.w, 0.f);
  }
  *(float4*)&out[(size_t)idx * 4] = o;
}

// ---------- launch ----------
extern "C" void kernel_launch(void* const* d_in, const int* in_sizes, int n_in,
                              void* d_out, int out_size, void* d_ws,
                              size_t ws_size, hipStream_t stream) {
  const int* x_atom = (const int*)d_in[0];
  const int* x_chir = (const int*)d_in[1];
  const int* esrc = (const int*)d_in[2];
  const int* edst = (const int*)d_in[3];
  const int* etype = (const int*)d_in[4];
  const int* edir = (const int*)d_in[5];
  const float* x_emb1 = (const float*)d_in[6];
  const float* x_emb2 = (const float*)d_in[7];
  const float* eemb1 = (const float*)d_in[8];
  const float* eemb2 = (const float*)d_in[9];
  const float* W1 = (const float*)d_in[10];
  const float* b1 = (const float*)d_in[11];
  const float* W2 = (const float*)d_in[12];
  const float* b2 = (const float*)d_in[13];
  const float* gamma = (const float*)d_in[14];
  const float* beta = (const float*)d_in[15];

  const int N = in_sizes[0];
  const int E = in_sizes[2];

  // ws layout: ping-pong bufA/bufB (each N*1024 BYTES = max(N*256 f32,
  // N*512 bf16)), aggb, weights, CSR, stats
  char* ws = (char*)d_ws;
  size_t off = 0;
  float* bufA = (float*)(ws + off); off += (size_t)N * 1024;
  float* bufB = (float*)(ws + off); off += (size_t)N * 1024;
  u16* aggb = (u16*)(ws + off); off += (size_t)N * 256 * 2;
  u16* w1t = (u16*)(ws + off); off += (size_t)5 * 512 * 256 * 2;
  u16* w2t = (u16*)(ws + off); off += (size_t)5 * 256 * 512 * 2;
  int* rp = (int*)(ws + off); off += (size_t)(N + 1) * 4;
  int* degcur = (int*)(ws + off); off += (size_t)N * 4;
  int* bsum = (int*)(ws + off); off += 512 * 4;
  int* bexcl = (int*)(ws + off); off += 512 * 4;
  u32* adj = (u32*)(ws + off); off += (size_t)E * 4;
  float* stats = (float*)(ws + off); off += 4096;

  const int gN64 = (N * 64 + 255) / 256;
  const int gMB = (N + 127) / 128;
  const int gE = (E + 255) / 256;
  const int B1 = (N + 255) / 256;

  // --- CSR build (once per call; deterministic work) ---
  hipMemsetAsync(degcur, 0, (size_t)N * 4, stream);
  k_deg_count<<<gE, 256, 0, stream>>>(edst, degcur, E);
  k_scan1<<<B1, 256, 0, stream>>>(degcur, rp, bsum, N);
  k_scan2<<<1, 512, 0, stream>>>(bsum, bexcl, B1);
  k_scan3<<<B1, 256, 0, stream>>>(rp, bexcl, degcur, N, E);
  k_fill<<<gE, 256, 0, stream>>>(esrc, edst, etype, edir, degcur, adj, E);

  k_cast_weights<<<(2 * 5 * 512 * 256 + 255) / 256, 256, 0, stream>>>(W1, W2,
                                                                      w1t, w2t);
  k_node_init<<<gN64, 256, 0, stream>>>(x_atom, x_chir, x_emb1, x_emb2, bufA, N);

  for (int l = 0; l < 5; ++l) {
    const float* ee1 = eemb1 + (size_t)l * 6 * 256;
    const float* ee2 = eemb2 + (size_t)l * 3 * 256;
    float* h = (l & 1) ? bufB : bufA;      // layer input
    float* other = (l & 1) ? bufA : bufB;  // GEMM2 out / BN in-place
    u16* interb = (u16*)h;                 // h dead after gather

    k_gather<<<(N + 3) / 4, 256, 0, stream>>>(h, rp, adj, ee1, ee2, aggb, N);
    k_gemm<256, 512, true><<<dim3(gMB, 4), 256, 0, stream>>>(
        aggb, w1t + (size_t)l * 512 * 256, b1 + l * 512, interb, N);
    k_gemm<512, 256, false><<<dim3(gMB, 2), 256, 0, stream>>>(
        interb, w2t + (size_t)l * 256 * 512, b2 + l * 256, other, N);
    hipMemsetAsync(stats, 0, 2048, stream);
    k_bn_stats<<<512, 256, 0, stream>>>(other, stats, N);
    k_bn_finalize<<<1, 256, 0, stream>>>(stats, gamma, beta, l, 1.f / N);
    if (l < 4)
      k_bn_apply<true><<<gN64, 256, 0, stream>>>(other, stats, other, N);
    else
      k_bn_apply<false><<<gN64, 256, 0, stream>>>(other, stats, (float*)d_out, N);
  }
}

// Round 4
// 1725.644 us; speedup vs baseline: 8.4890x; 1.1540x over previous
//
#include <hip/hip_runtime.h>
#include <cstdint>

typedef float f32x4 __attribute__((ext_vector_type(4)));
typedef __bf16 bf16x8 __attribute__((ext_vector_type(8)));
typedef unsigned short ushort4v __attribute__((ext_vector_type(4)));
typedef unsigned short u16;
typedef unsigned int u32;

// ---------- helpers ----------
__device__ __forceinline__ u16 f2bf(float f) {
  u32 u = __builtin_bit_cast(u32, f);
  u32 r = (u + 0x7fffu + ((u >> 16) & 1u)) >> 16;
  return (u16)r;
}

__device__ __forceinline__ void gload_lds16(const void* g, void* lds) {
  __builtin_amdgcn_global_load_lds(
      (const __attribute__((address_space(1))) u32*)g,
      (__attribute__((address_space(3))) u32*)lds,
      16, 0, 0);
}

// ---------- one-time: cast + transpose weights to bf16 ----------
__global__ __launch_bounds__(256) void k_cast_weights(
    const float* __restrict__ W1, const float* __restrict__ W2,
    u16* __restrict__ w1t, u16* __restrict__ w2t) {
  const int PER = 5 * 512 * 256;
  int idx = blockIdx.x * 256 + threadIdx.x;
  if (idx < PER) {
    int l = idx / (512 * 256);
    int rem = idx % (512 * 256);
    int n = rem / 256, k = rem % 256;
    w1t[idx] = f2bf(W1[l * 131072 + k * 512 + n]);
  } else if (idx < 2 * PER) {
    int j = idx - PER;
    int l = j / (256 * 512);
    int rem = j % (256 * 512);
    int n = rem / 512, k = rem % 512;
    w2t[j] = f2bf(W2[l * 131072 + k * 256 + n]);
  }
}

// ---------- node input embedding ----------
__global__ __launch_bounds__(256) void k_node_init(
    const int* __restrict__ xa, const int* __restrict__ xc,
    const float* __restrict__ e1, const float* __restrict__ e2,
    float* __restrict__ h, int N) {
  int idx = blockIdx.x * 256 + threadIdx.x;
  if (idx >= N * 64) return;
  int node = idx >> 6, c = (idx & 63) * 4;
  int a = xa[node], ch = xc[node];
  float4 v1 = *(const float4*)&e1[a * 256 + c];
  float4 v2 = *(const float4*)&e2[ch * 256 + c];
  float4 o = make_float4(v1.x + v2.x, v1.y + v2.y, v1.z + v2.z, v1.w + v2.w);
  *(float4*)&h[(size_t)node * 256 + c] = o;
}

// ---------- CSR build ----------
__global__ __launch_bounds__(256) void k_deg_count(
    const int* __restrict__ dst, int* __restrict__ deg, int E) {
  int e = blockIdx.x * 256 + threadIdx.x;
  if (e < E) atomicAdd(&deg[dst[e]], 1);
}

__global__ __launch_bounds__(256) void k_scan1(
    const int* __restrict__ deg, int* __restrict__ rp,
    int* __restrict__ bsum, int N) {
  __shared__ int s[256];
  int i = blockIdx.x * 256 + threadIdx.x;
  int v = (i < N) ? deg[i] : 0;
  s[threadIdx.x] = v;
  __syncthreads();
#pragma unroll
  for (int off = 1; off < 256; off <<= 1) {
    int t = (threadIdx.x >= off) ? s[threadIdx.x - off] : 0;
    __syncthreads();
    s[threadIdx.x] += t;
    __syncthreads();
  }
  if (i < N) rp[i] = s[threadIdx.x] - v;
  if (threadIdx.x == 255) bsum[blockIdx.x] = s[255];
}

__global__ __launch_bounds__(512) void k_scan2(
    const int* __restrict__ bsum, int* __restrict__ bexcl, int B) {
  __shared__ int s[512];
  int v = (threadIdx.x < B) ? bsum[threadIdx.x] : 0;
  s[threadIdx.x] = v;
  __syncthreads();
#pragma unroll
  for (int off = 1; off < 512; off <<= 1) {
    int t = (threadIdx.x >= off) ? s[threadIdx.x - off] : 0;
    __syncthreads();
    s[threadIdx.x] += t;
    __syncthreads();
  }
  if (threadIdx.x < B) bexcl[threadIdx.x] = s[threadIdx.x] - v;
}

__global__ __launch_bounds__(256) void k_scan3(
    int* __restrict__ rp, const int* __restrict__ bexcl,
    int* __restrict__ cur, int N, int E) {
  int i = blockIdx.x * 256 + threadIdx.x;
  if (i < N) {
    int v = rp[i] + bexcl[blockIdx.x];
    rp[i] = v;
    cur[i] = v;
  }
  if (i == 0) rp[N] = E;
}

__global__ __launch_bounds__(256) void k_fill(
    const int* __restrict__ src, const int* __restrict__ dst,
    const int* __restrict__ et, const int* __restrict__ ed,
    int* __restrict__ cur, u32* __restrict__ adj, int E) {
  int e = blockIdx.x * 256 + threadIdx.x;
  if (e >= E) return;
  int pos = atomicAdd(&cur[dst[e]], 1);
  adj[pos] = (u32)src[e] | ((u32)et[e] << 17) | ((u32)ed[e] << 20);
}

// ---------- gather-aggregate (optionally applying BN+relu to h on the fly) --
template <bool BN>
__global__ __launch_bounds__(256) void k_gather(
    const float* __restrict__ h, const float* __restrict__ stats,
    const int* __restrict__ rp, const u32* __restrict__ adj,
    const float* __restrict__ ee1, const float* __restrict__ ee2,
    u16* __restrict__ aggb, int N) {
  int node = blockIdx.x * 4 + (threadIdx.x >> 6);
  if (node >= N) return;
  int lane = threadIdx.x & 63;
  int c = lane * 4;
  float4 sc, sh;
  if (BN) {
    sc = *(const float4*)&stats[512 + c];
    sh = *(const float4*)&stats[768 + c];
  }
  // self loop: edge attr [4, 0]
  float4 hv = *(const float4*)&h[(size_t)node * 256 + c];
  if (BN) {
    hv.x = fmaxf(hv.x * sc.x + sh.x, 0.f);
    hv.y = fmaxf(hv.y * sc.y + sh.y, 0.f);
    hv.z = fmaxf(hv.z * sc.z + sh.z, 0.f);
    hv.w = fmaxf(hv.w * sc.w + sh.w, 0.f);
  }
  float4 e1v = *(const float4*)&ee1[4 * 256 + c];
  float4 e2v = *(const float4*)&ee2[c];
  float ax = hv.x + e1v.x + e2v.x, ay = hv.y + e1v.y + e2v.y;
  float az = hv.z + e1v.z + e2v.z, aw = hv.w + e1v.w + e2v.w;
  int beg = rp[node], end = rp[node + 1];
  for (int i = beg; i < end; ++i) {
    u32 p = adj[i];
    int s = p & 0x1FFFF;
    int t = (p >> 17) & 7;
    int r = (p >> 20) & 3;
    float4 sv = *(const float4*)&h[(size_t)s * 256 + c];
    if (BN) {
      sv.x = fmaxf(sv.x * sc.x + sh.x, 0.f);
      sv.y = fmaxf(sv.y * sc.y + sh.y, 0.f);
      sv.z = fmaxf(sv.z * sc.z + sh.z, 0.f);
      sv.w = fmaxf(sv.w * sc.w + sh.w, 0.f);
    }
    float4 a = *(const float4*)&ee1[t * 256 + c];
    float4 b = *(const float4*)&ee2[r * 256 + c];
    ax += sv.x + a.x + b.x;
    ay += sv.y + a.y + b.y;
    az += sv.z + a.z + b.z;
    aw += sv.w + a.w + b.w;
  }
  ushort4v o;
  o[0] = f2bf(ax); o[1] = f2bf(ay); o[2] = f2bf(az); o[3] = f2bf(aw);
  *(ushort4v*)&aggb[(size_t)node * 256 + c] = o;
}

// ---------- MFMA GEMM: BM=64, BN=NC (full width), 8 waves, BK=32 ----------
// A[M,K] bf16, Bt[NC,K] bf16. LDS XOR-swizzle ((fr&3)<<4) both sides.
// RELU_BF16: fused bias+relu+bf16 store. STATS: per-block per-channel
// sum/sumsq partials to pb[bid*512 + {c, 256+c}].
template <int K, int NC, bool RELU_BF16, bool STATS>
__global__ __launch_bounds__(512) void k_gemm64(
    const u16* __restrict__ A, const u16* __restrict__ Bt,
    const float* __restrict__ bias, void* __restrict__ outp,
    float* __restrict__ pb, int M) {
  constexpr int NF = NC / 128;          // col-frags per wave
  constexpr int TC = 256 + NC * 4;      // 16B chunks per K-step
  constexpr int JN = (TC + 511) / 512;
  __shared__ u16 As[64 * 32];
  __shared__ u16 Bs[NC * 32];
  const int tid = threadIdx.x;
  const int lane = tid & 63;
  const int wv = tid >> 6;              // 0..7
  const int m0 = blockIdx.x * 64;
  const int fr = lane & 15;
  const int kgb = (lane >> 4) * 16;     // fragment k-offset in bytes
  const int swz = (fr & 3) << 4;

  f32x4 acc[4][NF];
#pragma unroll
  for (int m = 0; m < 4; ++m)
#pragma unroll
    for (int n = 0; n < NF; ++n) acc[m][n] = (f32x4){0.f, 0.f, 0.f, 0.f};

  for (int k0 = 0; k0 < K; k0 += 32) {
    __syncthreads();
#pragma unroll
    for (int j = 0; j < JN; ++j) {
      const int c0 = j * 512 + wv * 64;  // wave-uniform chunk base
      const int c = c0 + lane;
      if (c0 < 256) {  // A tile: 64 rows x 32 (4 chunks/row)
        int row = c >> 2, q = (c & 3) ^ (row & 3);
        int ar = m0 + row;
        if (ar >= M) ar = M - 1;
        gload_lds16(A + (size_t)ar * K + k0 + q * 8, (char*)As + c0 * 16);
      } else if (c0 < TC) {  // B tile: NC rows x 32
        int cb = c - 256;
        int row = cb >> 2, q = (cb & 3) ^ (row & 3);
        gload_lds16(Bt + (size_t)row * K + k0 + q * 8,
                    (char*)Bs + (c0 - 256) * 16);
      }
    }
    __syncthreads();
    bf16x8 af[4], bf[NF];
#pragma unroll
    for (int m = 0; m < 4; ++m)
      af[m] = *(const bf16x8*)((const char*)As + (m * 16 + fr) * 64 +
                               (kgb ^ swz));
#pragma unroll
    for (int n = 0; n < NF; ++n)
      bf[n] = *(const bf16x8*)((const char*)Bs +
                               (wv * (NC / 8) + n * 16 + fr) * 64 +
                               (kgb ^ swz));
#pragma unroll
    for (int m = 0; m < 4; ++m)
#pragma unroll
      for (int n = 0; n < NF; ++n)
        acc[m][n] = __builtin_amdgcn_mfma_f32_16x16x32_bf16(af[m], bf[n],
                                                            acc[m][n], 0, 0, 0);
  }

  const int rb = (lane >> 4) * 4;
  float s[NF], s2[NF];
#pragma unroll
  for (int n = 0; n < NF; ++n) { s[n] = 0.f; s2[n] = 0.f; }
#pragma unroll
  for (int m = 0; m < 4; ++m) {
#pragma unroll
    for (int n = 0; n < NF; ++n) {
      const int col = wv * (NC / 8) + n * 16 + fr;
      const float bv = bias[col];
#pragma unroll
      for (int j = 0; j < 4; ++j) {
        const int row = m0 + m * 16 + rb + j;
        if (row < M) {
          float v = acc[m][n][j] + bv;
          if (RELU_BF16) {
            v = fmaxf(v, 0.f);
            ((u16*)outp)[(size_t)row * NC + col] = f2bf(v);
          } else {
            ((float*)outp)[(size_t)row * NC + col] = v;
          }
          if (STATS) {
            s[n] += v;
            s2[n] += v * v;
          }
        }
      }
    }
  }
  if (STATS) {
#pragma unroll
    for (int n = 0; n < NF; ++n) {
      s[n] += __shfl_xor(s[n], 16);
      s[n] += __shfl_xor(s[n], 32);
      s2[n] += __shfl_xor(s2[n], 16);
      s2[n] += __shfl_xor(s2[n], 32);
    }
    if (lane < 16) {
#pragma unroll
      for (int n = 0; n < NF; ++n) {
        const int col = wv * (NC / 8) + n * 16 + fr;
        pb[(size_t)blockIdx.x * 512 + col] = s[n];
        pb[(size_t)blockIdx.x * 512 + 256 + col] = s2[n];
      }
    }
  }
}

// ---------- BN partial reduce + finalize ----------
__global__ __launch_bounds__(256) void k_bnred(
    const float* __restrict__ pb, float* __restrict__ stats, int NB) {
  int c = threadIdx.x;
  float s = 0.f, s2 = 0.f;
  for (int b = blockIdx.x; b < NB; b += gridDim.x) {
    s += pb[(size_t)b * 512 + c];
    s2 += pb[(size_t)b * 512 + 256 + c];
  }
  unsafeAtomicAdd(&stats[c], s);
  unsafeAtomicAdd(&stats[256 + c], s2);
}

__global__ __launch_bounds__(256) void k_bn_finalize(
    float* __restrict__ stats, const float* __restrict__ gamma,
    const float* __restrict__ beta, int l, float invN) {
  int c = threadIdx.x;
  float mean = stats[c] * invN;
  float var = stats[256 + c] * invN - mean * mean;
  float sc = gamma[l * 256 + c] * rsqrtf(var + 1e-5f);
  stats[512 + c] = sc;
  stats[768 + c] = beta[l * 256 + c] - mean * sc;
}

// ---------- final BN apply (last layer only, no relu) ----------
__global__ __launch_bounds__(256) void k_bn_apply(
    const float* __restrict__ hl, const float* __restrict__ stats,
    float* __restrict__ out, int N) {
  int idx = blockIdx.x * 256 + threadIdx.x;
  if (idx >= N * 64) return;
  int c = (idx & 63) * 4;
  float4 v = *(const float4*)&hl[(size_t)idx * 4];
  float4 sc = *(const float4*)&stats[512 + c];
  float4 sh = *(const float4*)&stats[768 + c];
  float4 o = make_float4(v.x * sc.x + sh.x, v.y * sc.y + sh.y,
                         v.z * sc.z + sh.z, v.w * sc.w + sh.w);
  *(float4*)&out[(size_t)idx * 4] = o;
}

// ---------- launch ----------
extern "C" void kernel_launch(void* const* d_in, const int* in_sizes, int n_in,
                              void* d_out, int out_size, void* d_ws,
                              size_t ws_size, hipStream_t stream) {
  const int* x_atom = (const int*)d_in[0];
  const int* x_chir = (const int*)d_in[1];
  const int* esrc = (const int*)d_in[2];
  const int* edst = (const int*)d_in[3];
  const int* etype = (const int*)d_in[4];
  const int* edir = (const int*)d_in[5];
  const float* x_emb1 = (const float*)d_in[6];
  const float* x_emb2 = (const float*)d_in[7];
  const float* eemb1 = (const float*)d_in[8];
  const float* eemb2 = (const float*)d_in[9];
  const float* W1 = (const float*)d_in[10];
  const float* b1 = (const float*)d_in[11];
  const float* W2 = (const float*)d_in[12];
  const float* b2 = (const float*)d_in[13];
  const float* gamma = (const float*)d_in[14];
  const float* beta = (const float*)d_in[15];

  const int N = in_sizes[0];
  const int E = in_sizes[2];

  char* ws = (char*)d_ws;
  size_t off = 0;
  float* bufA = (float*)(ws + off); off += (size_t)N * 1024;
  float* bufB = (float*)(ws + off); off += (size_t)N * 1024;
  u16* aggb = (u16*)(ws + off); off += (size_t)N * 256 * 2;
  u16* w1t = (u16*)(ws + off); off += (size_t)5 * 512 * 256 * 2;
  u16* w2t = (u16*)(ws + off); off += (size_t)5 * 256 * 512 * 2;
  int* rp = (int*)(ws + off); off += (size_t)(N + 1) * 4;
  int* degcur = (int*)(ws + off); off += (size_t)N * 4;
  int* bsum = (int*)(ws + off); off += 512 * 4;
  int* bexcl = (int*)(ws + off); off += 512 * 4;
  u32* adj = (u32*)(ws + off); off += (size_t)E * 4;
  const int NB64 = (N + 63) / 64;  // GEMM row-blocks (1563)
  float* pb = (float*)(ws + off); off += (size_t)NB64 * 512 * 4;
  float* statsAll = (float*)(ws + off); off += 5 * 1024 * 4;  // per-layer

  const int gN64 = (N * 64 + 255) / 256;
  const int gE = (E + 255) / 256;
  const int B1 = (N + 255) / 256;

  // --- one-time: CSR build + weight cast + node embed + stats zero ---
  hipMemsetAsync(degcur, 0, (size_t)N * 4, stream);
  hipMemsetAsync(statsAll, 0, 5 * 1024 * 4, stream);
  k_deg_count<<<gE, 256, 0, stream>>>(edst, degcur, E);
  k_scan1<<<B1, 256, 0, stream>>>(degcur, rp, bsum, N);
  k_scan2<<<1, 512, 0, stream>>>(bsum, bexcl, B1);
  k_scan3<<<B1, 256, 0, stream>>>(rp, bexcl, degcur, N, E);
  k_fill<<<gE, 256, 0, stream>>>(esrc, edst, etype, edir, degcur, adj, E);
  k_cast_weights<<<(2 * 5 * 512 * 256 + 255) / 256, 256, 0, stream>>>(W1, W2,
                                                                      w1t, w2t);
  k_node_init<<<gN64, 256, 0, stream>>>(x_atom, x_chir, x_emb1, x_emb2, bufA, N);

  for (int l = 0; l < 5; ++l) {
    const float* ee1 = eemb1 + (size_t)l * 6 * 256;
    const float* ee2 = eemb2 + (size_t)l * 3 * 256;
    float* in = (l & 1) ? bufB : bufA;     // raw layer input (h0 or hl-1 raw)
    float* out = (l & 1) ? bufA : bufB;    // raw GEMM2 output
    u16* interb = (u16*)in;                // input dead after gather
    float* st = statsAll + l * 1024;
    float* stPrev = statsAll + (l - 1) * 1024;

    if (l == 0)
      k_gather<false><<<(N + 3) / 4, 256, 0, stream>>>(in, nullptr, rp, adj,
                                                       ee1, ee2, aggb, N);
    else
      k_gather<true><<<(N + 3) / 4, 256, 0, stream>>>(in, stPrev, rp, adj,
                                                      ee1, ee2, aggb, N);
    k_gemm64<256, 512, true, false><<<NB64, 512, 0, stream>>>(
        aggb, w1t + (size_t)l * 512 * 256, b1 + l * 512, interb, nullptr, N);
    k_gemm64<512, 256, false, true><<<NB64, 512, 0, stream>>>(
        interb, w2t + (size_t)l * 256 * 512, b2 + l * 256, out, pb, N);
    k_bnred<<<32, 256, 0, stream>>>(pb, st, NB64);
    k_bn_finalize<<<1, 256, 0, stream>>>(st, gamma, beta, l, 1.f / N);
    if (l == 4)
      k_bn_apply<<<gN64, 256, 0, stream>>>(out, st, (float*)d_out, N);
  }
}

// Round 5
// 1724.655 us; speedup vs baseline: 8.4939x; 1.0006x over previous
//
#include <hip/hip_runtime.h>
#include <cstdint>

typedef float f32x4 __attribute__((ext_vector_type(4)));
typedef __bf16 bf16x8 __attribute__((ext_vector_type(8)));
typedef unsigned short ushort4v __attribute__((ext_vector_type(4)));
typedef unsigned short u16;
typedef unsigned int u32;

// ---------- helpers ----------
__device__ __forceinline__ u16 f2bf(float f) {
  u32 u = __builtin_bit_cast(u32, f);
  u32 r = (u + 0x7fffu + ((u >> 16) & 1u)) >> 16;
  return (u16)r;
}

__device__ __forceinline__ void gload_lds16(const void* g, void* lds) {
  __builtin_amdgcn_global_load_lds(
      (const __attribute__((address_space(1))) u32*)g,
      (__attribute__((address_space(3))) u32*)lds,
      16, 0, 0);
}

// ---------- one-time: cast + transpose weights to bf16 ----------
__global__ __launch_bounds__(256) void k_cast_weights(
    const float* __restrict__ W1, const float* __restrict__ W2,
    u16* __restrict__ w1t, u16* __restrict__ w2t) {
  const int PER = 5 * 512 * 256;
  int idx = blockIdx.x * 256 + threadIdx.x;
  if (idx < PER) {
    int l = idx / (512 * 256);
    int rem = idx % (512 * 256);
    int n = rem / 256, k = rem % 256;
    w1t[idx] = f2bf(W1[l * 131072 + k * 512 + n]);
  } else if (idx < 2 * PER) {
    int j = idx - PER;
    int l = j / (256 * 512);
    int rem = j % (256 * 512);
    int n = rem / 512, k = rem % 512;
    w2t[j] = f2bf(W2[l * 131072 + k * 256 + n]);
  }
}

// ---------- node input embedding ----------
__global__ __launch_bounds__(256) void k_node_init(
    const int* __restrict__ xa, const int* __restrict__ xc,
    const float* __restrict__ e1, const float* __restrict__ e2,
    float* __restrict__ h, int N) {
  int idx = blockIdx.x * 256 + threadIdx.x;
  if (idx >= N * 64) return;
  int node = idx >> 6, c = (idx & 63) * 4;
  int a = xa[node], ch = xc[node];
  float4 v1 = *(const float4*)&e1[a * 256 + c];
  float4 v2 = *(const float4*)&e2[ch * 256 + c];
  float4 o = make_float4(v1.x + v2.x, v1.y + v2.y, v1.z + v2.z, v1.w + v2.w);
  *(float4*)&h[(size_t)node * 256 + c] = o;
}

// ---------- CSR build ----------
__global__ __launch_bounds__(256) void k_deg_count(
    const int* __restrict__ dst, int* __restrict__ deg, int E) {
  int e = blockIdx.x * 256 + threadIdx.x;
  if (e < E) atomicAdd(&deg[dst[e]], 1);
}

__global__ __launch_bounds__(256) void k_scan1(
    const int* __restrict__ deg, int* __restrict__ rp,
    int* __restrict__ bsum, int N) {
  __shared__ int s[256];
  int i = blockIdx.x * 256 + threadIdx.x;
  int v = (i < N) ? deg[i] : 0;
  s[threadIdx.x] = v;
  __syncthreads();
#pragma unroll
  for (int off = 1; off < 256; off <<= 1) {
    int t = (threadIdx.x >= off) ? s[threadIdx.x - off] : 0;
    __syncthreads();
    s[threadIdx.x] += t;
    __syncthreads();
  }
  if (i < N) rp[i] = s[threadIdx.x] - v;
  if (threadIdx.x == 255) bsum[blockIdx.x] = s[255];
}

__global__ __launch_bounds__(512) void k_scan2(
    const int* __restrict__ bsum, int* __restrict__ bexcl, int B) {
  __shared__ int s[512];
  int v = (threadIdx.x < B) ? bsum[threadIdx.x] : 0;
  s[threadIdx.x] = v;
  __syncthreads();
#pragma unroll
  for (int off = 1; off < 512; off <<= 1) {
    int t = (threadIdx.x >= off) ? s[threadIdx.x - off] : 0;
    __syncthreads();
    s[threadIdx.x] += t;
    __syncthreads();
  }
  if (threadIdx.x < B) bexcl[threadIdx.x] = s[threadIdx.x] - v;
}

__global__ __launch_bounds__(256) void k_scan3(
    int* __restrict__ rp, const int* __restrict__ bexcl,
    int* __restrict__ cur, int N, int E) {
  int i = blockIdx.x * 256 + threadIdx.x;
  if (i < N) {
    int v = rp[i] + bexcl[blockIdx.x];
    rp[i] = v;
    cur[i] = v;
  }
  if (i == 0) rp[N] = E;
}

__global__ __launch_bounds__(256) void k_fill(
    const int* __restrict__ src, const int* __restrict__ dst,
    const int* __restrict__ et, const int* __restrict__ ed,
    int* __restrict__ cur, u32* __restrict__ adj, int E) {
  int e = blockIdx.x * 256 + threadIdx.x;
  if (e >= E) return;
  int pos = atomicAdd(&cur[dst[e]], 1);
  adj[pos] = (u32)src[e] | ((u32)et[e] << 17) | ((u32)ed[e] << 20);
}

// ---------- gather-aggregate (optionally applying BN+relu to h on the fly) --
template <bool BN>
__global__ __launch_bounds__(256) void k_gather(
    const float* __restrict__ h, const float* __restrict__ stats,
    const int* __restrict__ rp, const u32* __restrict__ adj,
    const float* __restrict__ ee1, const float* __restrict__ ee2,
    u16* __restrict__ aggb, int N) {
  int node = blockIdx.x * 4 + (threadIdx.x >> 6);
  if (node >= N) return;
  int lane = threadIdx.x & 63;
  int c = lane * 4;
  float4 sc, sh;
  if (BN) {
    sc = *(const float4*)&stats[512 + c];
    sh = *(const float4*)&stats[768 + c];
  }
  // self loop: edge attr [4, 0]
  float4 hv = *(const float4*)&h[(size_t)node * 256 + c];
  if (BN) {
    hv.x = fmaxf(hv.x * sc.x + sh.x, 0.f);
    hv.y = fmaxf(hv.y * sc.y + sh.y, 0.f);
    hv.z = fmaxf(hv.z * sc.z + sh.z, 0.f);
    hv.w = fmaxf(hv.w * sc.w + sh.w, 0.f);
  }
  float4 e1v = *(const float4*)&ee1[4 * 256 + c];
  float4 e2v = *(const float4*)&ee2[c];
  float ax = hv.x + e1v.x + e2v.x, ay = hv.y + e1v.y + e2v.y;
  float az = hv.z + e1v.z + e2v.z, aw = hv.w + e1v.w + e2v.w;
  int beg = rp[node], end = rp[node + 1];
  for (int i = beg; i < end; ++i) {
    u32 p = adj[i];
    int s = p & 0x1FFFF;
    int t = (p >> 17) & 7;
    int r = (p >> 20) & 3;
    float4 sv = *(const float4*)&h[(size_t)s * 256 + c];
    if (BN) {
      sv.x = fmaxf(sv.x * sc.x + sh.x, 0.f);
      sv.y = fmaxf(sv.y * sc.y + sh.y, 0.f);
      sv.z = fmaxf(sv.z * sc.z + sh.z, 0.f);
      sv.w = fmaxf(sv.w * sc.w + sh.w, 0.f);
    }
    float4 a = *(const float4*)&ee1[t * 256 + c];
    float4 b = *(const float4*)&ee2[r * 256 + c];
    ax += sv.x + a.x + b.x;
    ay += sv.y + a.y + b.y;
    az += sv.z + a.z + b.z;
    aw += sv.w + a.w + b.w;
  }
  ushort4v o;
  o[0] = f2bf(ax); o[1] = f2bf(ay); o[2] = f2bf(az); o[3] = f2bf(aw);
  *(ushort4v*)&aggb[(size_t)node * 256 + c] = o;
}

// ---------- MFMA GEMM: m97 structure. 128x128 tile, 4 waves (2x2), BK=32.
// A[M,K] bf16, Bt[NC,K] bf16 (grid.y picks 128-col panel). XOR-swizzled LDS.
// RELU_BF16: fused bias+relu+bf16 store. STATS: per-channel sum/sumsq
// reduced in LDS then atomically added to st[{c, 256+c}].
template <int K, int NC, bool RELU_BF16, bool STATS>
__global__ __launch_bounds__(256) void k_gemm128(
    const u16* __restrict__ A, const u16* __restrict__ Bt,
    const float* __restrict__ bias, void* __restrict__ outp,
    float* __restrict__ st, int M) {
  __shared__ u16 As[128 * 32];
  __shared__ u16 Bs[128 * 32];
  const int tid = threadIdx.x;
  const int lane = tid & 63;
  const int wv = tid >> 6;
  const int wrow = wv >> 1, wcol = wv & 1;
  const int m0 = blockIdx.x * 128;
  const int n0 = blockIdx.y * 128;
  const int fr = lane & 15;
  const int kgb = (lane >> 4) * 16;  // fragment k-offset in bytes
  const int swz = (fr & 3) << 4;

  f32x4 acc[4][4];
#pragma unroll
  for (int m = 0; m < 4; ++m)
#pragma unroll
    for (int n = 0; n < 4; ++n) acc[m][n] = (f32x4){0.f, 0.f, 0.f, 0.f};

  for (int k0 = 0; k0 < K; k0 += 32) {
    __syncthreads();
#pragma unroll
    for (int j = 0; j < 4; ++j) {
      const int c0 = j * 256 + (tid & ~63);  // wave-uniform chunk base
      const int c = j * 256 + tid;
      if (j < 2) {  // A tile: 128 rows x 32 cols, 4 chunks/row, swizzled src
        int row = c >> 2, q = (c & 3) ^ (row & 3);
        int ar = m0 + row;
        if (ar >= M) ar = M - 1;
        gload_lds16(A + (size_t)ar * K + k0 + q * 8, (char*)As + c0 * 16);
      } else {  // B tile
        int cb = c - 512;
        int row = cb >> 2, q = (cb & 3) ^ (row & 3);
        gload_lds16(Bt + (size_t)(n0 + row) * K + k0 + q * 8,
                    (char*)Bs + (c0 - 512) * 16);
      }
    }
    __syncthreads();
    bf16x8 af[4], bf[4];
#pragma unroll
    for (int m = 0; m < 4; ++m)
      af[m] = *(const bf16x8*)((const char*)As +
                               (wrow * 64 + m * 16 + fr) * 64 + (kgb ^ swz));
#pragma unroll
    for (int n = 0; n < 4; ++n)
      bf[n] = *(const bf16x8*)((const char*)Bs +
                               (wcol * 64 + n * 16 + fr) * 64 + (kgb ^ swz));
#pragma unroll
    for (int m = 0; m < 4; ++m)
#pragma unroll
      for (int n = 0; n < 4; ++n)
        acc[m][n] = __builtin_amdgcn_mfma_f32_16x16x32_bf16(af[m], bf[n],
                                                            acc[m][n], 0, 0, 0);
  }

  float* sst = (float*)As;  // 256 floats: [0..127]=sum, [128..255]=sumsq
  if (STATS) {
    __syncthreads();  // all waves done reading As
    sst[tid] = 0.f;
    __syncthreads();
  }

  const int rb = (lane >> 4) * 4;
  float s[4], s2[4];
#pragma unroll
  for (int n = 0; n < 4; ++n) { s[n] = 0.f; s2[n] = 0.f; }
#pragma unroll
  for (int m = 0; m < 4; ++m) {
#pragma unroll
    for (int n = 0; n < 4; ++n) {
      const int col = n0 + wcol * 64 + n * 16 + fr;
      const float bv = bias[col];
#pragma unroll
      for (int j = 0; j < 4; ++j) {
        const int row = m0 + wrow * 64 + m * 16 + rb + j;
        if (row < M) {
          float v = acc[m][n][j] + bv;
          if (RELU_BF16) {
            v = fmaxf(v, 0.f);
            ((u16*)outp)[(size_t)row * NC + col] = f2bf(v);
          } else {
            ((float*)outp)[(size_t)row * NC + col] = v;
          }
          if (STATS) {
            s[n] += v;
            s2[n] += v * v;
          }
        }
      }
    }
  }
  if (STATS) {
#pragma unroll
    for (int n = 0; n < 4; ++n) {
      s[n] += __shfl_xor(s[n], 16);
      s[n] += __shfl_xor(s[n], 32);
      s2[n] += __shfl_xor(s2[n], 16);
      s2[n] += __shfl_xor(s2[n], 32);
    }
    if (lane < 16) {
#pragma unroll
      for (int n = 0; n < 4; ++n) {
        atomicAdd(&sst[wcol * 64 + n * 16 + fr], s[n]);
        atomicAdd(&sst[128 + wcol * 64 + n * 16 + fr], s2[n]);
      }
    }
    __syncthreads();
    // tid<128 -> sum of channel n0+tid ; tid>=128 -> sumsq
    const int ch = n0 + (tid & 127);
    unsafeAtomicAdd(&st[(tid < 128 ? 0 : 256) + ch], sst[tid]);
  }
}

__global__ __launch_bounds__(256) void k_bn_finalize(
    float* __restrict__ stats, const float* __restrict__ gamma,
    const float* __restrict__ beta, int l, float invN) {
  int c = threadIdx.x;
  float mean = stats[c] * invN;
  float var = stats[256 + c] * invN - mean * mean;
  float sc = gamma[l * 256 + c] * rsqrtf(var + 1e-5f);
  stats[512 + c] = sc;
  stats[768 + c] = beta[l * 256 + c] - mean * sc;
}

// ---------- final BN apply (last layer only, no relu) ----------
__global__ __launch_bounds__(256) void k_bn_apply(
    const float* __restrict__ hl, const float* __restrict__ stats,
    float* __restrict__ out, int N) {
  int idx = blockIdx.x * 256 + threadIdx.x;
  if (idx >= N * 64) return;
  int c = (idx & 63) * 4;
  float4 v = *(const float4*)&hl[(size_t)idx * 4];
  float4 sc = *(const float4*)&stats[512 + c];
  float4 sh = *(const float4*)&stats[768 + c];
  float4 o = make_float4(v.x * sc.x + sh.x, v.y * sc.y + sh.y,
                         v.z * sc.z + sh.z, v.w * sc.w + sh.w);
  *(float4*)&out[(size_t)idx * 4] = o;
}

// ---------- launch ----------
extern "C" void kernel_launch(void* const* d_in, const int* in_sizes, int n_in,
                              void* d_out, int out_size, void* d_ws,
                              size_t ws_size, hipStream_t stream) {
  const int* x_atom = (const int*)d_in[0];
  const int* x_chir = (const int*)d_in[1];
  const int* esrc = (const int*)d_in[2];
  const int* edst = (const int*)d_in[3];
  const int* etype = (const int*)d_in[4];
  const int* edir = (const int*)d_in[5];
  const float* x_emb1 = (const float*)d_in[6];
  const float* x_emb2 = (const float*)d_in[7];
  const float* eemb1 = (const float*)d_in[8];
  const float* eemb2 = (const float*)d_in[9];
  const float* W1 = (const float*)d_in[10];
  const float* b1 = (const float*)d_in[11];
  const float* W2 = (const float*)d_in[12];
  const float* b2 = (const float*)d_in[13];
  const float* gamma = (const float*)d_in[14];
  const float* beta = (const float*)d_in[15];

  const int N = in_sizes[0];
  const int E = in_sizes[2];

  char* ws = (char*)d_ws;
  size_t off = 0;
  float* bufA = (float*)(ws + off); off += (size_t)N * 1024;
  float* bufB = (float*)(ws + off); off += (size_t)N * 1024;
  u16* aggb = (u16*)(ws + off); off += (size_t)N * 256 * 2;
  u16* w1t = (u16*)(ws + off); off += (size_t)5 * 512 * 256 * 2;
  u16* w2t = (u16*)(ws + off); off += (size_t)5 * 256 * 512 * 2;
  int* rp = (int*)(ws + off); off += (size_t)(N + 1) * 4;
  int* degcur = (int*)(ws + off); off += (size_t)N * 4;
  int* bsum = (int*)(ws + off); off += 512 * 4;
  int* bexcl = (int*)(ws + off); off += 512 * 4;
  u32* adj = (u32*)(ws + off); off += (size_t)E * 4;
  float* statsAll = (float*)(ws + off); off += 5 * 1024 * 4;  // per-layer

  const int gN64 = (N * 64 + 255) / 256;
  const int gE = (E + 255) / 256;
  const int B1 = (N + 255) / 256;
  const int NB128 = (N + 127) / 128;  // 782

  // --- one-time: CSR build + weight cast + node embed + stats zero ---
  hipMemsetAsync(degcur, 0, (size_t)N * 4, stream);
  hipMemsetAsync(statsAll, 0, 5 * 1024 * 4, stream);
  k_deg_count<<<gE, 256, 0, stream>>>(edst, degcur, E);
  k_scan1<<<B1, 256, 0, stream>>>(degcur, rp, bsum, N);
  k_scan2<<<1, 512, 0, stream>>>(bsum, bexcl, B1);
  k_scan3<<<B1, 256, 0, stream>>>(rp, bexcl, degcur, N, E);
  k_fill<<<gE, 256, 0, stream>>>(esrc, edst, etype, edir, degcur, adj, E);
  k_cast_weights<<<(2 * 5 * 512 * 256 + 255) / 256, 256, 0, stream>>>(W1, W2,
                                                                      w1t, w2t);
  k_node_init<<<gN64, 256, 0, stream>>>(x_atom, x_chir, x_emb1, x_emb2, bufA, N);

  for (int l = 0; l < 5; ++l) {
    const float* ee1 = eemb1 + (size_t)l * 6 * 256;
    const float* ee2 = eemb2 + (size_t)l * 3 * 256;
    float* in = (l & 1) ? bufB : bufA;     // raw layer input (h0 or hl-1 raw)
    float* out = (l & 1) ? bufA : bufB;    // raw GEMM2 output
    u16* interb = (u16*)in;                // input dead after gather
    float* st = statsAll + l * 1024;
    float* stPrev = statsAll + (l - 1) * 1024;

    if (l == 0)
      k_gather<false><<<(N + 3) / 4, 256, 0, stream>>>(in, nullptr, rp, adj,
                                                       ee1, ee2, aggb, N);
    else
      k_gather<true><<<(N + 3) / 4, 256, 0, stream>>>(in, stPrev, rp, adj,
                                                      ee1, ee2, aggb, N);
    k_gemm128<256, 512, true, false><<<dim3(NB128, 4), 256, 0, stream>>>(
        aggb, w1t + (size_t)l * 512 * 256, b1 + l * 512, interb, nullptr, N);
    k_gemm128<512, 256, false, true><<<dim3(NB128, 2), 256, 0, stream>>>(
        interb, w2t + (size_t)l * 256 * 512, b2 + l * 256, out, st, N);
    k_bn_finalize<<<1, 256, 0, stream>>>(st, gamma, beta, l, 1.f / N);
    if (l == 4)
      k_bn_apply<<<gN64, 256, 0, stream>>>(out, st, (float*)d_out, N);
  }
}

// Round 6
// 1642.748 us; speedup vs baseline: 8.9174x; 1.0499x over previous
//
#include <hip/hip_runtime.h>
#include <cstdint>

typedef float f32x4 __attribute__((ext_vector_type(4)));
typedef __bf16 bf16x8 __attribute__((ext_vector_type(8)));
typedef unsigned short ushort4v __attribute__((ext_vector_type(4)));
typedef unsigned short u16;
typedef unsigned int u32;

// ---------- helpers ----------
__device__ __forceinline__ u16 f2bf(float f) {
  u32 u = __builtin_bit_cast(u32, f);
  u32 r = (u + 0x7fffu + ((u >> 16) & 1u)) >> 16;
  return (u16)r;
}

__device__ __forceinline__ void gload_lds16(const void* g, void* lds) {
  __builtin_amdgcn_global_load_lds(
      (const __attribute__((address_space(1))) u32*)g,
      (__attribute__((address_space(3))) u32*)lds,
      16, 0, 0);
}

__device__ __forceinline__ void bnrelu4(float4& v, const float4& sc,
                                        const float4& sh) {
  v.x = fmaxf(v.x * sc.x + sh.x, 0.f);
  v.y = fmaxf(v.y * sc.y + sh.y, 0.f);
  v.z = fmaxf(v.z * sc.z + sh.z, 0.f);
  v.w = fmaxf(v.w * sc.w + sh.w, 0.f);
}

// ---------- one-time: cast + transpose weights to bf16 ----------
__global__ __launch_bounds__(256) void k_cast_weights(
    const float* __restrict__ W1, const float* __restrict__ W2,
    u16* __restrict__ w1t, u16* __restrict__ w2t) {
  const int PER = 5 * 512 * 256;
  int idx = blockIdx.x * 256 + threadIdx.x;
  if (idx < PER) {
    int l = idx / (512 * 256);
    int rem = idx % (512 * 256);
    int n = rem / 256, k = rem % 256;
    w1t[idx] = f2bf(W1[l * 131072 + k * 512 + n]);
  } else if (idx < 2 * PER) {
    int j = idx - PER;
    int l = j / (256 * 512);
    int rem = j % (256 * 512);
    int n = rem / 512, k = rem % 512;
    w2t[j] = f2bf(W2[l * 131072 + k * 256 + n]);
  }
}

// ---------- node input embedding ----------
__global__ __launch_bounds__(256) void k_node_init(
    const int* __restrict__ xa, const int* __restrict__ xc,
    const float* __restrict__ e1, const float* __restrict__ e2,
    float* __restrict__ h, int N) {
  int idx = blockIdx.x * 256 + threadIdx.x;
  if (idx >= N * 64) return;
  int node = idx >> 6, c = (idx & 63) * 4;
  int a = xa[node], ch = xc[node];
  float4 v1 = *(const float4*)&e1[a * 256 + c];
  float4 v2 = *(const float4*)&e2[ch * 256 + c];
  float4 o = make_float4(v1.x + v2.x, v1.y + v2.y, v1.z + v2.z, v1.w + v2.w);
  *(float4*)&h[(size_t)node * 256 + c] = o;
}

// ---------- CSR build ----------
__global__ __launch_bounds__(256) void k_deg_count(
    const int* __restrict__ dst, int* __restrict__ deg, int E) {
  int e = blockIdx.x * 256 + threadIdx.x;
  if (e < E) atomicAdd(&deg[dst[e]], 1);
}

__global__ __launch_bounds__(256) void k_scan1(
    const int* __restrict__ deg, int* __restrict__ rp,
    int* __restrict__ bsum, int N) {
  __shared__ int s[256];
  int i = blockIdx.x * 256 + threadIdx.x;
  int v = (i < N) ? deg[i] : 0;
  s[threadIdx.x] = v;
  __syncthreads();
#pragma unroll
  for (int off = 1; off < 256; off <<= 1) {
    int t = (threadIdx.x >= off) ? s[threadIdx.x - off] : 0;
    __syncthreads();
    s[threadIdx.x] += t;
    __syncthreads();
  }
  if (i < N) rp[i] = s[threadIdx.x] - v;
  if (threadIdx.x == 255) bsum[blockIdx.x] = s[255];
}

__global__ __launch_bounds__(512) void k_scan2(
    const int* __restrict__ bsum, int* __restrict__ bexcl, int B) {
  __shared__ int s[512];
  int v = (threadIdx.x < B) ? bsum[threadIdx.x] : 0;
  s[threadIdx.x] = v;
  __syncthreads();
#pragma unroll
  for (int off = 1; off < 512; off <<= 1) {
    int t = (threadIdx.x >= off) ? s[threadIdx.x - off] : 0;
    __syncthreads();
    s[threadIdx.x] += t;
    __syncthreads();
  }
  if (threadIdx.x < B) bexcl[threadIdx.x] = s[threadIdx.x] - v;
}

__global__ __launch_bounds__(256) void k_scan3(
    int* __restrict__ rp, const int* __restrict__ bexcl,
    int* __restrict__ cur, int N, int E) {
  int i = blockIdx.x * 256 + threadIdx.x;
  if (i < N) {
    int v = rp[i] + bexcl[blockIdx.x];
    rp[i] = v;
    cur[i] = v;
  }
  if (i == 0) rp[N] = E;
}

__global__ __launch_bounds__(256) void k_fill(
    const int* __restrict__ src, const int* __restrict__ dst,
    const int* __restrict__ et, const int* __restrict__ ed,
    int* __restrict__ cur, u32* __restrict__ adj, int E) {
  int e = blockIdx.x * 256 + threadIdx.x;
  if (e >= E) return;
  int pos = atomicAdd(&cur[dst[e]], 1);
  adj[pos] = (u32)src[e] | ((u32)et[e] << 17) | ((u32)ed[e] << 20);
}

// ---------- gather-aggregate ----------
// agg[n] = bnrelu(h[n]) + sum_in bnrelu(h[src])  + per-type-count * ee rows.
// Unrolled x4 with independent accumulators (latency-chain break); edge-embed
// work hoisted to epilogue via packed per-type/dir counts.
template <bool BN>
__global__ __launch_bounds__(256) void k_gather(
    const float* __restrict__ h, const float* __restrict__ stats,
    const int* __restrict__ rp, const u32* __restrict__ adj,
    const float* __restrict__ ee1, const float* __restrict__ ee2,
    u16* __restrict__ aggb, int N) {
  int node = blockIdx.x * 4 + (threadIdx.x >> 6);
  if (node >= N) return;
  int lane = threadIdx.x & 63;
  int c = lane * 4;
  float4 sc, sh;
  if (BN) {
    sc = *(const float4*)&stats[512 + c];
    sh = *(const float4*)&stats[768 + c];
  }
  // self node term
  float4 hv = *(const float4*)&h[(size_t)node * 256 + c];
  if (BN) bnrelu4(hv, sc, sh);
  float4 a0 = hv;
  float4 a1 = make_float4(0.f, 0.f, 0.f, 0.f);
  float4 a2 = a1, a3 = a1;
  // packed counts: tcA = cnt[t=0..3] (8b each); tcB = cnt[t=4] | cnt[r=0]<<8
  // | cnt[r=1]<<16
  u32 tcA = 0, tcB = 0;
  int beg = rp[node], end = rp[node + 1];
  int i = beg;
  for (; i + 4 <= end; i += 4) {
    u32 p0 = adj[i], p1 = adj[i + 1], p2 = adj[i + 2], p3 = adj[i + 3];
    float4 v0 = *(const float4*)&h[(size_t)(p0 & 0x1FFFF) * 256 + c];
    float4 v1 = *(const float4*)&h[(size_t)(p1 & 0x1FFFF) * 256 + c];
    float4 v2 = *(const float4*)&h[(size_t)(p2 & 0x1FFFF) * 256 + c];
    float4 v3 = *(const float4*)&h[(size_t)(p3 & 0x1FFFF) * 256 + c];
    if (BN) {
      bnrelu4(v0, sc, sh); bnrelu4(v1, sc, sh);
      bnrelu4(v2, sc, sh); bnrelu4(v3, sc, sh);
    }
    a0.x += v0.x; a0.y += v0.y; a0.z += v0.z; a0.w += v0.w;
    a1.x += v1.x; a1.y += v1.y; a1.z += v1.z; a1.w += v1.w;
    a2.x += v2.x; a2.y += v2.y; a2.z += v2.z; a2.w += v2.w;
    a3.x += v3.x; a3.y += v3.y; a3.z += v3.z; a3.w += v3.w;
#pragma unroll
    for (int u = 0; u < 4; ++u) {
      u32 p = (u == 0) ? p0 : (u == 1) ? p1 : (u == 2) ? p2 : p3;
      u32 t = (p >> 17) & 7, r = (p >> 20) & 3;
      tcA += (t < 4) ? (1u << (t * 8)) : 0u;
      tcB += ((t == 4) ? 1u : 0u) + ((r == 0) ? 256u : 0u) +
             ((r == 1) ? 65536u : 0u);
    }
  }
  for (; i < end; ++i) {
    u32 p = adj[i];
    float4 v = *(const float4*)&h[(size_t)(p & 0x1FFFF) * 256 + c];
    if (BN) bnrelu4(v, sc, sh);
    a0.x += v.x; a0.y += v.y; a0.z += v.z; a0.w += v.w;
    u32 t = (p >> 17) & 7, r = (p >> 20) & 3;
    tcA += (t < 4) ? (1u << (t * 8)) : 0u;
    tcB += ((t == 4) ? 1u : 0u) + ((r == 0) ? 256u : 0u) +
           ((r == 1) ? 65536u : 0u);
  }
  // unpack counts (+ self-loop edge attr [4, 0])
  int deg = end - beg;
  int i0 = tcA & 255, i1 = (tcA >> 8) & 255, i2 = (tcA >> 16) & 255,
      i3 = (tcA >> 24) & 255;
  int i4 = (int)(tcB & 255) + 1;
  int r0 = (int)((tcB >> 8) & 255) + 1;
  int r1 = (int)((tcB >> 16) & 255);
  int i5 = deg - i0 - i1 - i2 - i3 - (i4 - 1);
  int r2 = deg - (r0 - 1) - r1;
  float ct[6], cr[3];
  ct[0] = (float)i0; ct[1] = (float)i1; ct[2] = (float)i2;
  ct[3] = (float)i3; ct[4] = (float)i4; ct[5] = (float)i5;
  cr[0] = (float)r0; cr[1] = (float)r1; cr[2] = (float)r2;

  float ax = a0.x + a1.x + a2.x + a3.x;
  float ay = a0.y + a1.y + a2.y + a3.y;
  float az = a0.z + a1.z + a2.z + a3.z;
  float aw = a0.w + a1.w + a2.w + a3.w;
#pragma unroll
  for (int t = 0; t < 6; ++t) {
    float4 e = *(const float4*)&ee1[t * 256 + c];
    ax += ct[t] * e.x; ay += ct[t] * e.y;
    az += ct[t] * e.z; aw += ct[t] * e.w;
  }
#pragma unroll
  for (int r = 0; r < 3; ++r) {
    float4 e = *(const float4*)&ee2[r * 256 + c];
    ax += cr[r] * e.x; ay += cr[r] * e.y;
    az += cr[r] * e.z; aw += cr[r] * e.w;
  }
  ushort4v o;
  o[0] = f2bf(ax); o[1] = f2bf(ay); o[2] = f2bf(az); o[3] = f2bf(aw);
  *(ushort4v*)&aggb[(size_t)node * 256 + c] = o;
}

// ---------- MFMA GEMM: 128x128 tile, 4 waves (2x2), BK=32, XOR-swizzled LDS.
template <int K, int NC, bool RELU_BF16, bool STATS>
__global__ __launch_bounds__(256) void k_gemm128(
    const u16* __restrict__ A, const u16* __restrict__ Bt,
    const float* __restrict__ bias, void* __restrict__ outp,
    float* __restrict__ st, int M) {
  __shared__ u16 As[128 * 32];
  __shared__ u16 Bs[128 * 32];
  const int tid = threadIdx.x;
  const int lane = tid & 63;
  const int wv = tid >> 6;
  const int wrow = wv >> 1, wcol = wv & 1;
  const int m0 = blockIdx.x * 128;
  const int n0 = blockIdx.y * 128;
  const int fr = lane & 15;
  const int kgb = (lane >> 4) * 16;  // fragment k-offset in bytes
  const int swz = (fr & 3) << 4;

  f32x4 acc[4][4];
#pragma unroll
  for (int m = 0; m < 4; ++m)
#pragma unroll
    for (int n = 0; n < 4; ++n) acc[m][n] = (f32x4){0.f, 0.f, 0.f, 0.f};

  for (int k0 = 0; k0 < K; k0 += 32) {
    __syncthreads();
#pragma unroll
    for (int j = 0; j < 4; ++j) {
      const int c0 = j * 256 + (tid & ~63);  // wave-uniform chunk base
      const int c = j * 256 + tid;
      if (j < 2) {  // A tile
        int row = c >> 2, q = (c & 3) ^ (row & 3);
        int ar = m0 + row;
        if (ar >= M) ar = M - 1;
        gload_lds16(A + (size_t)ar * K + k0 + q * 8, (char*)As + c0 * 16);
      } else {  // B tile
        int cb = c - 512;
        int row = cb >> 2, q = (cb & 3) ^ (row & 3);
        gload_lds16(Bt + (size_t)(n0 + row) * K + k0 + q * 8,
                    (char*)Bs + (c0 - 512) * 16);
      }
    }
    __syncthreads();
    bf16x8 af[4], bf[4];
#pragma unroll
    for (int m = 0; m < 4; ++m)
      af[m] = *(const bf16x8*)((const char*)As +
                               (wrow * 64 + m * 16 + fr) * 64 + (kgb ^ swz));
#pragma unroll
    for (int n = 0; n < 4; ++n)
      bf[n] = *(const bf16x8*)((const char*)Bs +
                               (wcol * 64 + n * 16 + fr) * 64 + (kgb ^ swz));
#pragma unroll
    for (int m = 0; m < 4; ++m)
#pragma unroll
      for (int n = 0; n < 4; ++n)
        acc[m][n] = __builtin_amdgcn_mfma_f32_16x16x32_bf16(af[m], bf[n],
                                                            acc[m][n], 0, 0, 0);
  }

  float* sst = (float*)As;  // 256 floats: [0..127]=sum, [128..255]=sumsq
  if (STATS) {
    __syncthreads();
    sst[tid] = 0.f;
    __syncthreads();
  }

  const int rb = (lane >> 4) * 4;
  float s[4], s2[4];
#pragma unroll
  for (int n = 0; n < 4; ++n) { s[n] = 0.f; s2[n] = 0.f; }
#pragma unroll
  for (int m = 0; m < 4; ++m) {
#pragma unroll
    for (int n = 0; n < 4; ++n) {
      const int col = n0 + wcol * 64 + n * 16 + fr;
      const float bv = bias[col];
#pragma unroll
      for (int j = 0; j < 4; ++j) {
        const int row = m0 + wrow * 64 + m * 16 + rb + j;
        if (row < M) {
          float v = acc[m][n][j] + bv;
          if (RELU_BF16) {
            v = fmaxf(v, 0.f);
            ((u16*)outp)[(size_t)row * NC + col] = f2bf(v);
          } else {
            ((float*)outp)[(size_t)row * NC + col] = v;
          }
          if (STATS) {
            s[n] += v;
            s2[n] += v * v;
          }
        }
      }
    }
  }
  if (STATS) {
#pragma unroll
    for (int n = 0; n < 4; ++n) {
      s[n] += __shfl_xor(s[n], 16);
      s[n] += __shfl_xor(s[n], 32);
      s2[n] += __shfl_xor(s2[n], 16);
      s2[n] += __shfl_xor(s2[n], 32);
    }
    if (lane < 16) {
#pragma unroll
      for (int n = 0; n < 4; ++n) {
        atomicAdd(&sst[wcol * 64 + n * 16 + fr], s[n]);
        atomicAdd(&sst[128 + wcol * 64 + n * 16 + fr], s2[n]);
      }
    }
    __syncthreads();
    const int ch = n0 + (tid & 127);
    unsafeAtomicAdd(&st[(tid < 128 ? 0 : 256) + ch], sst[tid]);
  }
}

__global__ __launch_bounds__(256) void k_bn_finalize(
    float* __restrict__ stats, const float* __restrict__ gamma,
    const float* __restrict__ beta, int l, float invN) {
  int c = threadIdx.x;
  float mean = stats[c] * invN;
  float var = stats[256 + c] * invN - mean * mean;
  float sc = gamma[l * 256 + c] * rsqrtf(var + 1e-5f);
  stats[512 + c] = sc;
  stats[768 + c] = beta[l * 256 + c] - mean * sc;
}

// ---------- final BN apply (last layer only, no relu) ----------
__global__ __launch_bounds__(256) void k_bn_apply(
    const float* __restrict__ hl, const float* __restrict__ stats,
    float* __restrict__ out, int N) {
  int idx = blockIdx.x * 256 + threadIdx.x;
  if (idx >= N * 64) return;
  int c = (idx & 63) * 4;
  float4 v = *(const float4*)&hl[(size_t)idx * 4];
  float4 sc = *(const float4*)&stats[512 + c];
  float4 sh = *(const float4*)&stats[768 + c];
  float4 o = make_float4(v.x * sc.x + sh.x, v.y * sc.y + sh.y,
                         v.z * sc.z + sh.z, v.w * sc.w + sh.w);
  *(float4*)&out[(size_t)idx * 4] = o;
}

// ---------- launch ----------
extern "C" void kernel_launch(void* const* d_in, const int* in_sizes, int n_in,
                              void* d_out, int out_size, void* d_ws,
                              size_t ws_size, hipStream_t stream) {
  const int* x_atom = (const int*)d_in[0];
  const int* x_chir = (const int*)d_in[1];
  const int* esrc = (const int*)d_in[2];
  const int* edst = (const int*)d_in[3];
  const int* etype = (const int*)d_in[4];
  const int* edir = (const int*)d_in[5];
  const float* x_emb1 = (const float*)d_in[6];
  const float* x_emb2 = (const float*)d_in[7];
  const float* eemb1 = (const float*)d_in[8];
  const float* eemb2 = (const float*)d_in[9];
  const float* W1 = (const float*)d_in[10];
  const float* b1 = (const float*)d_in[11];
  const float* W2 = (const float*)d_in[12];
  const float* b2 = (const float*)d_in[13];
  const float* gamma = (const float*)d_in[14];
  const float* beta = (const float*)d_in[15];

  const int N = in_sizes[0];
  const int E = in_sizes[2];

  char* ws = (char*)d_ws;
  size_t off = 0;
  float* bufA = (float*)(ws + off); off += (size_t)N * 1024;
  float* bufB = (float*)(ws + off); off += (size_t)N * 1024;
  u16* aggb = (u16*)(ws + off); off += (size_t)N * 256 * 2;
  u16* w1t = (u16*)(ws + off); off += (size_t)5 * 512 * 256 * 2;
  u16* w2t = (u16*)(ws + off); off += (size_t)5 * 256 * 512 * 2;
  int* rp = (int*)(ws + off); off += (size_t)(N + 1) * 4;
  int* degcur = (int*)(ws + off); off += (size_t)N * 4;
  int* bsum = (int*)(ws + off); off += 512 * 4;
  int* bexcl = (int*)(ws + off); off += 512 * 4;
  u32* adj = (u32*)(ws + off); off += (size_t)E * 4;
  float* statsAll = (float*)(ws + off); off += 5 * 1024 * 4;  // per-layer

  const int gN64 = (N * 64 + 255) / 256;
  const int gE = (E + 255) / 256;
  const int B1 = (N + 255) / 256;
  const int NB128 = (N + 127) / 128;  // 782

  // --- one-time: CSR build + weight cast + node embed + stats zero ---
  hipMemsetAsync(degcur, 0, (size_t)N * 4, stream);
  hipMemsetAsync(statsAll, 0, 5 * 1024 * 4, stream);
  k_deg_count<<<gE, 256, 0, stream>>>(edst, degcur, E);
  k_scan1<<<B1, 256, 0, stream>>>(degcur, rp, bsum, N);
  k_scan2<<<1, 512, 0, stream>>>(bsum, bexcl, B1);
  k_scan3<<<B1, 256, 0, stream>>>(rp, bexcl, degcur, N, E);
  k_fill<<<gE, 256, 0, stream>>>(esrc, edst, etype, edir, degcur, adj, E);
  k_cast_weights<<<(2 * 5 * 512 * 256 + 255) / 256, 256, 0, stream>>>(W1, W2,
                                                                      w1t, w2t);
  k_node_init<<<gN64, 256, 0, stream>>>(x_atom, x_chir, x_emb1, x_emb2, bufA, N);

  for (int l = 0; l < 5; ++l) {
    const float* ee1 = eemb1 + (size_t)l * 6 * 256;
    const float* ee2 = eemb2 + (size_t)l * 3 * 256;
    float* in = (l & 1) ? bufB : bufA;     // raw layer input (h0 or hl-1 raw)
    float* out = (l & 1) ? bufA : bufB;    // raw GEMM2 output
    u16* interb = (u16*)in;                // input dead after gather
    float* st = statsAll + l * 1024;
    float* stPrev = statsAll + (l - 1) * 1024;

    if (l == 0)
      k_gather<false><<<(N + 3) / 4, 256, 0, stream>>>(in, nullptr, rp, adj,
                                                       ee1, ee2, aggb, N);
    else
      k_gather<true><<<(N + 3) / 4, 256, 0, stream>>>(in, stPrev, rp, adj,
                                                      ee1, ee2, aggb, N);
    k_gemm128<256, 512, true, false><<<dim3(NB128, 4), 256, 0, stream>>>(
        aggb, w1t + (size_t)l * 512 * 256, b1 + l * 512, interb, nullptr, N);
    k_gemm128<512, 256, false, true><<<dim3(NB128, 2), 256, 0, stream>>>(
        interb, w2t + (size_t)l * 256 * 512, b2 + l * 256, out, st, N);
    k_bn_finalize<<<1, 256, 0, stream>>>(st, gamma, beta, l, 1.f / N);
    if (l == 4)
      k_bn_apply<<<gN64, 256, 0, stream>>>(out, st, (float*)d_out, N);
  }
}

// Round 7
// 1625.181 us; speedup vs baseline: 9.0138x; 1.0108x over previous
//
#include <hip/hip_runtime.h>
#include <cstdint>

typedef float f32x4 __attribute__((ext_vector_type(4)));
typedef __bf16 bf16x8 __attribute__((ext_vector_type(8)));
typedef unsigned short ushort4v __attribute__((ext_vector_type(4)));
typedef unsigned short u16;
typedef unsigned int u32;

// ---------- helpers ----------
__device__ __forceinline__ u16 f2bf(float f) {
  u32 u = __builtin_bit_cast(u32, f);
  u32 r = (u + 0x7fffu + ((u >> 16) & 1u)) >> 16;
  return (u16)r;
}

__device__ __forceinline__ void gload_lds16(const void* g, void* lds) {
  __builtin_amdgcn_global_load_lds(
      (const __attribute__((address_space(1))) u32*)g,
      (__attribute__((address_space(3))) u32*)lds,
      16, 0, 0);
}

__device__ __forceinline__ void bnrelu4(float4& v, const float4& sc,
                                        const float4& sh) {
  v.x = fmaxf(v.x * sc.x + sh.x, 0.f);
  v.y = fmaxf(v.y * sc.y + sh.y, 0.f);
  v.z = fmaxf(v.z * sc.z + sh.z, 0.f);
  v.w = fmaxf(v.w * sc.w + sh.w, 0.f);
}

// ---------- one-time: cast + transpose weights to bf16 ----------
__global__ __launch_bounds__(256) void k_cast_weights(
    const float* __restrict__ W1, const float* __restrict__ W2,
    u16* __restrict__ w1t, u16* __restrict__ w2t) {
  const int PER = 5 * 512 * 256;
  int idx = blockIdx.x * 256 + threadIdx.x;
  if (idx < PER) {
    int l = idx / (512 * 256);
    int rem = idx % (512 * 256);
    int n = rem / 256, k = rem % 256;
    w1t[idx] = f2bf(W1[l * 131072 + k * 512 + n]);
  } else if (idx < 2 * PER) {
    int j = idx - PER;
    int l = j / (256 * 512);
    int rem = j % (256 * 512);
    int n = rem / 512, k = rem % 512;
    w2t[j] = f2bf(W2[l * 131072 + k * 256 + n]);
  }
}

// ---------- node input embedding ----------
__global__ __launch_bounds__(256) void k_node_init(
    const int* __restrict__ xa, const int* __restrict__ xc,
    const float* __restrict__ e1, const float* __restrict__ e2,
    float* __restrict__ h, int N) {
  int idx = blockIdx.x * 256 + threadIdx.x;
  if (idx >= N * 64) return;
  int node = idx >> 6, c = (idx & 63) * 4;
  int a = xa[node], ch = xc[node];
  float4 v1 = *(const float4*)&e1[a * 256 + c];
  float4 v2 = *(const float4*)&e2[ch * 256 + c];
  float4 o = make_float4(v1.x + v2.x, v1.y + v2.y, v1.z + v2.z, v1.w + v2.w);
  *(float4*)&h[(size_t)node * 256 + c] = o;
}

// ---------- CSR build ----------
__global__ __launch_bounds__(256) void k_deg_count(
    const int* __restrict__ dst, int* __restrict__ deg, int E) {
  int e = blockIdx.x * 256 + threadIdx.x;
  if (e < E) atomicAdd(&deg[dst[e]], 1);
}

__global__ __launch_bounds__(256) void k_scan1(
    const int* __restrict__ deg, int* __restrict__ rp,
    int* __restrict__ bsum, int N) {
  __shared__ int s[256];
  int i = blockIdx.x * 256 + threadIdx.x;
  int v = (i < N) ? deg[i] : 0;
  s[threadIdx.x] = v;
  __syncthreads();
#pragma unroll
  for (int off = 1; off < 256; off <<= 1) {
    int t = (threadIdx.x >= off) ? s[threadIdx.x - off] : 0;
    __syncthreads();
    s[threadIdx.x] += t;
    __syncthreads();
  }
  if (i < N) rp[i] = s[threadIdx.x] - v;
  if (threadIdx.x == 255) bsum[blockIdx.x] = s[255];
}

__global__ __launch_bounds__(512) void k_scan2(
    const int* __restrict__ bsum, int* __restrict__ bexcl, int B) {
  __shared__ int s[512];
  int v = (threadIdx.x < B) ? bsum[threadIdx.x] : 0;
  s[threadIdx.x] = v;
  __syncthreads();
#pragma unroll
  for (int off = 1; off < 512; off <<= 1) {
    int t = (threadIdx.x >= off) ? s[threadIdx.x - off] : 0;
    __syncthreads();
    s[threadIdx.x] += t;
    __syncthreads();
  }
  if (threadIdx.x < B) bexcl[threadIdx.x] = s[threadIdx.x] - v;
}

__global__ __launch_bounds__(256) void k_scan3(
    int* __restrict__ rp, const int* __restrict__ bexcl,
    int* __restrict__ cur, int N, int E) {
  int i = blockIdx.x * 256 + threadIdx.x;
  if (i < N) {
    int v = rp[i] + bexcl[blockIdx.x];
    rp[i] = v;
    cur[i] = v;
  }
  if (i == 0) rp[N] = E;
}

__global__ __launch_bounds__(256) void k_fill(
    const int* __restrict__ src, const int* __restrict__ dst,
    const int* __restrict__ et, const int* __restrict__ ed,
    int* __restrict__ cur, u32* __restrict__ adj, int E) {
  int e = blockIdx.x * 256 + threadIdx.x;
  if (e >= E) return;
  int pos = atomicAdd(&cur[dst[e]], 1);
  adj[pos] = (u32)src[e] | ((u32)et[e] << 17) | ((u32)ed[e] << 20);
}

// ---------- gather-aggregate (unchanged from round 6) ----------
template <bool BN>
__global__ __launch_bounds__(256) void k_gather(
    const float* __restrict__ h, const float* __restrict__ stats,
    const int* __restrict__ rp, const u32* __restrict__ adj,
    const float* __restrict__ ee1, const float* __restrict__ ee2,
    u16* __restrict__ aggb, int N) {
  int node = blockIdx.x * 4 + (threadIdx.x >> 6);
  if (node >= N) return;
  int lane = threadIdx.x & 63;
  int c = lane * 4;
  float4 sc, sh;
  if (BN) {
    sc = *(const float4*)&stats[512 + c];
    sh = *(const float4*)&stats[768 + c];
  }
  float4 hv = *(const float4*)&h[(size_t)node * 256 + c];
  if (BN) bnrelu4(hv, sc, sh);
  float4 a0 = hv;
  float4 a1 = make_float4(0.f, 0.f, 0.f, 0.f);
  float4 a2 = a1, a3 = a1;
  u32 tcA = 0, tcB = 0;
  int beg = rp[node], end = rp[node + 1];
  int i = beg;
  for (; i + 4 <= end; i += 4) {
    u32 p0 = adj[i], p1 = adj[i + 1], p2 = adj[i + 2], p3 = adj[i + 3];
    float4 v0 = *(const float4*)&h[(size_t)(p0 & 0x1FFFF) * 256 + c];
    float4 v1 = *(const float4*)&h[(size_t)(p1 & 0x1FFFF) * 256 + c];
    float4 v2 = *(const float4*)&h[(size_t)(p2 & 0x1FFFF) * 256 + c];
    float4 v3 = *(const float4*)&h[(size_t)(p3 & 0x1FFFF) * 256 + c];
    if (BN) {
      bnrelu4(v0, sc, sh); bnrelu4(v1, sc, sh);
      bnrelu4(v2, sc, sh); bnrelu4(v3, sc, sh);
    }
    a0.x += v0.x; a0.y += v0.y; a0.z += v0.z; a0.w += v0.w;
    a1.x += v1.x; a1.y += v1.y; a1.z += v1.z; a1.w += v1.w;
    a2.x += v2.x; a2.y += v2.y; a2.z += v2.z; a2.w += v2.w;
    a3.x += v3.x; a3.y += v3.y; a3.z += v3.z; a3.w += v3.w;
#pragma unroll
    for (int u = 0; u < 4; ++u) {
      u32 p = (u == 0) ? p0 : (u == 1) ? p1 : (u == 2) ? p2 : p3;
      u32 t = (p >> 17) & 7, r = (p >> 20) & 3;
      tcA += (t < 4) ? (1u << (t * 8)) : 0u;
      tcB += ((t == 4) ? 1u : 0u) + ((r == 0) ? 256u : 0u) +
             ((r == 1) ? 65536u : 0u);
    }
  }
  for (; i < end; ++i) {
    u32 p = adj[i];
    float4 v = *(const float4*)&h[(size_t)(p & 0x1FFFF) * 256 + c];
    if (BN) bnrelu4(v, sc, sh);
    a0.x += v.x; a0.y += v.y; a0.z += v.z; a0.w += v.w;
    u32 t = (p >> 17) & 7, r = (p >> 20) & 3;
    tcA += (t < 4) ? (1u << (t * 8)) : 0u;
    tcB += ((t == 4) ? 1u : 0u) + ((r == 0) ? 256u : 0u) +
           ((r == 1) ? 65536u : 0u);
  }
  int deg = end - beg;
  int i0 = tcA & 255, i1 = (tcA >> 8) & 255, i2 = (tcA >> 16) & 255,
      i3 = (tcA >> 24) & 255;
  int i4 = (int)(tcB & 255) + 1;
  int r0 = (int)((tcB >> 8) & 255) + 1;
  int r1 = (int)((tcB >> 16) & 255);
  int i5 = deg - i0 - i1 - i2 - i3 - (i4 - 1);
  int r2 = deg - (r0 - 1) - r1;
  float ct[6], cr[3];
  ct[0] = (float)i0; ct[1] = (float)i1; ct[2] = (float)i2;
  ct[3] = (float)i3; ct[4] = (float)i4; ct[5] = (float)i5;
  cr[0] = (float)r0; cr[1] = (float)r1; cr[2] = (float)r2;

  float ax = a0.x + a1.x + a2.x + a3.x;
  float ay = a0.y + a1.y + a2.y + a3.y;
  float az = a0.z + a1.z + a2.z + a3.z;
  float aw = a0.w + a1.w + a2.w + a3.w;
#pragma unroll
  for (int t = 0; t < 6; ++t) {
    float4 e = *(const float4*)&ee1[t * 256 + c];
    ax += ct[t] * e.x; ay += ct[t] * e.y;
    az += ct[t] * e.z; aw += ct[t] * e.w;
  }
#pragma unroll
  for (int r = 0; r < 3; ++r) {
    float4 e = *(const float4*)&ee2[r * 256 + c];
    ax += cr[r] * e.x; ay += cr[r] * e.y;
    az += cr[r] * e.z; aw += cr[r] * e.w;
  }
  ushort4v o;
  o[0] = f2bf(ax); o[1] = f2bf(ay); o[2] = f2bf(az); o[3] = f2bf(aw);
  *(ushort4v*)&aggb[(size_t)node * 256 + c] = o;
}

// ---------- MFMA GEMM: 128x128 tile, 4 waves (2x2), BK=32, XOR-swizzled LDS,
// 2-phase double-buffer: stage(k+1) issued before compute(k); counted
// s_waitcnt vmcnt(4) (next tile's 4 loads stay in flight) + raw s_barrier.
template <int K, int NC, bool RELU_BF16, bool STATS>
__global__ __launch_bounds__(256) void k_gemm128(
    const u16* __restrict__ A, const u16* __restrict__ Bt,
    const float* __restrict__ bias, void* __restrict__ outp,
    float* __restrict__ st, int M) {
  constexpr int NSTEP = K / 32;
  __shared__ u16 As[2][128 * 32];
  __shared__ u16 Bs[2][128 * 32];
  const int tid = threadIdx.x;
  const int lane = tid & 63;
  const int wv = tid >> 6;
  const int wrow = wv >> 1, wcol = wv & 1;
  const int m0 = blockIdx.x * 128;
  const int n0 = blockIdx.y * 128;
  const int fr = lane & 15;
  const int kgb = (lane >> 4) * 16;  // fragment k-offset in bytes
  const int swz = (fr & 3) << 4;

  f32x4 acc[4][4];
#pragma unroll
  for (int m = 0; m < 4; ++m)
#pragma unroll
    for (int n = 0; n < 4; ++n) acc[m][n] = (f32x4){0.f, 0.f, 0.f, 0.f};

  // stage one 128x32 A-tile + 128x32 B-tile into buffer b (4 loads/thread)
  auto stage = [&](int k0, int b) {
#pragma unroll
    for (int j = 0; j < 4; ++j) {
      const int c0 = j * 256 + (tid & ~63);  // wave-uniform chunk base
      const int c = j * 256 + tid;
      if (j < 2) {
        int row = c >> 2, q = (c & 3) ^ (row & 3);
        int ar = m0 + row;
        if (ar >= M) ar = M - 1;
        gload_lds16(A + (size_t)ar * K + k0 + q * 8, (char*)As[b] + c0 * 16);
      } else {
        int cb = c - 512;
        int row = cb >> 2, q = (cb & 3) ^ (row & 3);
        gload_lds16(Bt + (size_t)(n0 + row) * K + k0 + q * 8,
                    (char*)Bs[b] + (c0 - 512) * 16);
      }
    }
  };

  stage(0, 0);
  for (int ks = 0; ks < NSTEP; ++ks) {
    const int b = ks & 1;
    if (ks + 1 < NSTEP) {
      stage((ks + 1) * 32, b ^ 1);
      asm volatile("s_waitcnt vmcnt(4)" ::: "memory");  // my tile-k loads done
    } else {
      asm volatile("s_waitcnt vmcnt(0)" ::: "memory");
    }
    __builtin_amdgcn_sched_barrier(0);
    __builtin_amdgcn_s_barrier();  // all waves' tile-k staging complete
    __builtin_amdgcn_sched_barrier(0);
    bf16x8 af[4], bf[4];
#pragma unroll
    for (int m = 0; m < 4; ++m)
      af[m] = *(const bf16x8*)((const char*)As[b] +
                               (wrow * 64 + m * 16 + fr) * 64 + (kgb ^ swz));
#pragma unroll
    for (int n = 0; n < 4; ++n)
      bf[n] = *(const bf16x8*)((const char*)Bs[b] +
                               (wcol * 64 + n * 16 + fr) * 64 + (kgb ^ swz));
#pragma unroll
    for (int m = 0; m < 4; ++m)
#pragma unroll
      for (int n = 0; n < 4; ++n)
        acc[m][n] = __builtin_amdgcn_mfma_f32_16x16x32_bf16(af[m], bf[n],
                                                            acc[m][n], 0, 0, 0);
    __builtin_amdgcn_sched_barrier(0);
    __builtin_amdgcn_s_barrier();  // reads of buf b done; safe to overwrite
  }

  float* sst = (float*)As;  // 256 floats: [0..127]=sum, [128..255]=sumsq
  if (STATS) {
    __syncthreads();
    sst[tid] = 0.f;
    __syncthreads();
  }

  const int rb = (lane >> 4) * 4;
  float s[4], s2[4];
#pragma unroll
  for (int n = 0; n < 4; ++n) { s[n] = 0.f; s2[n] = 0.f; }
#pragma unroll
  for (int m = 0; m < 4; ++m) {
#pragma unroll
    for (int n = 0; n < 4; ++n) {
      const int col = n0 + wcol * 64 + n * 16 + fr;
      const float bv = bias[col];
#pragma unroll
      for (int j = 0; j < 4; ++j) {
        const int row = m0 + wrow * 64 + m * 16 + rb + j;
        if (row < M) {
          float v = acc[m][n][j] + bv;
          if (RELU_BF16) {
            v = fmaxf(v, 0.f);
            ((u16*)outp)[(size_t)row * NC + col] = f2bf(v);
          } else {
            ((float*)outp)[(size_t)row * NC + col] = v;
          }
          if (STATS) {
            s[n] += v;
            s2[n] += v * v;
          }
        }
      }
    }
  }
  if (STATS) {
#pragma unroll
    for (int n = 0; n < 4; ++n) {
      s[n] += __shfl_xor(s[n], 16);
      s[n] += __shfl_xor(s[n], 32);
      s2[n] += __shfl_xor(s2[n], 16);
      s2[n] += __shfl_xor(s2[n], 32);
    }
    if (lane < 16) {
#pragma unroll
      for (int n = 0; n < 4; ++n) {
        atomicAdd(&sst[wcol * 64 + n * 16 + fr], s[n]);
        atomicAdd(&sst[128 + wcol * 64 + n * 16 + fr], s2[n]);
      }
    }
    __syncthreads();
    const int ch = n0 + (tid & 127);
    unsafeAtomicAdd(&st[(tid < 128 ? 0 : 256) + ch], sst[tid]);
  }
}

__global__ __launch_bounds__(256) void k_bn_finalize(
    float* __restrict__ stats, const float* __restrict__ gamma,
    const float* __restrict__ beta, int l, float invN) {
  int c = threadIdx.x;
  float mean = stats[c] * invN;
  float var = stats[256 + c] * invN - mean * mean;
  float sc = gamma[l * 256 + c] * rsqrtf(var + 1e-5f);
  stats[512 + c] = sc;
  stats[768 + c] = beta[l * 256 + c] - mean * sc;
}

// ---------- final BN apply (last layer only, no relu) ----------
__global__ __launch_bounds__(256) void k_bn_apply(
    const float* __restrict__ hl, const float* __restrict__ stats,
    float* __restrict__ out, int N) {
  int idx = blockIdx.x * 256 + threadIdx.x;
  if (idx >= N * 64) return;
  int c = (idx & 63) * 4;
  float4 v = *(const float4*)&hl[(size_t)idx * 4];
  float4 sc = *(const float4*)&stats[512 + c];
  float4 sh = *(const float4*)&stats[768 + c];
  float4 o = make_float4(v.x * sc.x + sh.x, v.y * sc.y + sh.y,
                         v.z * sc.z + sh.z, v.w * sc.w + sh.w);
  *(float4*)&out[(size_t)idx * 4] = o;
}

// ---------- launch ----------
extern "C" void kernel_launch(void* const* d_in, const int* in_sizes, int n_in,
                              void* d_out, int out_size, void* d_ws,
                              size_t ws_size, hipStream_t stream) {
  const int* x_atom = (const int*)d_in[0];
  const int* x_chir = (const int*)d_in[1];
  const int* esrc = (const int*)d_in[2];
  const int* edst = (const int*)d_in[3];
  const int* etype = (const int*)d_in[4];
  const int* edir = (const int*)d_in[5];
  const float* x_emb1 = (const float*)d_in[6];
  const float* x_emb2 = (const float*)d_in[7];
  const float* eemb1 = (const float*)d_in[8];
  const float* eemb2 = (const float*)d_in[9];
  const float* W1 = (const float*)d_in[10];
  const float* b1 = (const float*)d_in[11];
  const float* W2 = (const float*)d_in[12];
  const float* b2 = (const float*)d_in[13];
  const float* gamma = (const float*)d_in[14];
  const float* beta = (const float*)d_in[15];

  const int N = in_sizes[0];
  const int E = in_sizes[2];

  char* ws = (char*)d_ws;
  size_t off = 0;
  float* bufA = (float*)(ws + off); off += (size_t)N * 1024;
  float* bufB = (float*)(ws + off); off += (size_t)N * 1024;
  u16* aggb = (u16*)(ws + off); off += (size_t)N * 256 * 2;
  u16* w1t = (u16*)(ws + off); off += (size_t)5 * 512 * 256 * 2;
  u16* w2t = (u16*)(ws + off); off += (size_t)5 * 256 * 512 * 2;
  int* rp = (int*)(ws + off); off += (size_t)(N + 1) * 4;
  int* degcur = (int*)(ws + off); off += (size_t)N * 4;
  int* bsum = (int*)(ws + off); off += 512 * 4;
  int* bexcl = (int*)(ws + off); off += 512 * 4;
  u32* adj = (u32*)(ws + off); off += (size_t)E * 4;
  float* statsAll = (float*)(ws + off); off += 5 * 1024 * 4;  // per-layer

  const int gN64 = (N * 64 + 255) / 256;
  const int gE = (E + 255) / 256;
  const int B1 = (N + 255) / 256;
  const int NB128 = (N + 127) / 128;  // 782

  // --- one-time: CSR build + weight cast + node embed + stats zero ---
  hipMemsetAsync(degcur, 0, (size_t)N * 4, stream);
  hipMemsetAsync(statsAll, 0, 5 * 1024 * 4, stream);
  k_deg_count<<<gE, 256, 0, stream>>>(edst, degcur, E);
  k_scan1<<<B1, 256, 0, stream>>>(degcur, rp, bsum, N);
  k_scan2<<<1, 512, 0, stream>>>(bsum, bexcl, B1);
  k_scan3<<<B1, 256, 0, stream>>>(rp, bexcl, degcur, N, E);
  k_fill<<<gE, 256, 0, stream>>>(esrc, edst, etype, edir, degcur, adj, E);
  k_cast_weights<<<(2 * 5 * 512 * 256 + 255) / 256, 256, 0, stream>>>(W1, W2,
                                                                      w1t, w2t);
  k_node_init<<<gN64, 256, 0, stream>>>(x_atom, x_chir, x_emb1, x_emb2, bufA, N);

  for (int l = 0; l < 5; ++l) {
    const float* ee1 = eemb1 + (size_t)l * 6 * 256;
    const float* ee2 = eemb2 + (size_t)l * 3 * 256;
    float* in = (l & 1) ? bufB : bufA;     // raw layer input (h0 or hl-1 raw)
    float* out = (l & 1) ? bufA : bufB;    // raw GEMM2 output
    u16* interb = (u16*)in;                // input dead after gather
    float* st = statsAll + l * 1024;
    float* stPrev = statsAll + (l - 1) * 1024;

    if (l == 0)
      k_gather<false><<<(N + 3) / 4, 256, 0, stream>>>(in, nullptr, rp, adj,
                                                       ee1, ee2, aggb, N);
    else
      k_gather<true><<<(N + 3) / 4, 256, 0, stream>>>(in, stPrev, rp, adj,
                                                      ee1, ee2, aggb, N);
    k_gemm128<256, 512, true, false><<<dim3(NB128, 4), 256, 0, stream>>>(
        aggb, w1t + (size_t)l * 512 * 256, b1 + l * 512, interb, nullptr, N);
    k_gemm128<512, 256, false, true><<<dim3(NB128, 2), 256, 0, stream>>>(
        interb, w2t + (size_t)l * 256 * 512, b2 + l * 256, out, st, N);
    k_bn_finalize<<<1, 256, 0, stream>>>(st, gamma, beta, l, 1.f / N);
    if (l == 4)
      k_bn_apply<<<gN64, 256, 0, stream>>>(out, st, (float*)d_out, N);
  }
}

// Round 9
// 1415.865 us; speedup vs baseline: 10.3463x; 1.1478x over previous
//
#include <hip/hip_runtime.h>
#include <cstdint>

typedef float f32x4 __attribute__((ext_vector_type(4)));
typedef __bf16 bf16x8 __attribute__((ext_vector_type(8)));
typedef unsigned short ushort4v __attribute__((ext_vector_type(4)));
typedef unsigned short u16;
typedef unsigned int u32;

// ---------- helpers ----------
__device__ __forceinline__ u16 f2bf(float f) {
  u32 u = __builtin_bit_cast(u32, f);
  u32 r = (u + 0x7fffu + ((u >> 16) & 1u)) >> 16;
  return (u16)r;
}

__device__ __forceinline__ float4 b2f4(ushort4v v) {
  float4 o;
  o.x = __builtin_bit_cast(float, (u32)v[0] << 16);
  o.y = __builtin_bit_cast(float, (u32)v[1] << 16);
  o.z = __builtin_bit_cast(float, (u32)v[2] << 16);
  o.w = __builtin_bit_cast(float, (u32)v[3] << 16);
  return o;
}

__device__ __forceinline__ void gload_lds16(const void* g, void* lds) {
  __builtin_amdgcn_global_load_lds(
      (const __attribute__((address_space(1))) u32*)g,
      (__attribute__((address_space(3))) u32*)lds,
      16, 0, 0);
}

// ---------- one-time: cast + transpose weights to bf16 ----------
__global__ __launch_bounds__(256) void k_cast_weights(
    const float* __restrict__ W1, const float* __restrict__ W2,
    u16* __restrict__ w1t, u16* __restrict__ w2t) {
  const int PER = 5 * 512 * 256;
  int idx = blockIdx.x * 256 + threadIdx.x;
  if (idx < PER) {
    int l = idx / (512 * 256);
    int rem = idx % (512 * 256);
    int n = rem / 256, k = rem % 256;
    w1t[idx] = f2bf(W1[l * 131072 + k * 512 + n]);
  } else if (idx < 2 * PER) {
    int j = idx - PER;
    int l = j / (256 * 512);
    int rem = j % (256 * 512);
    int n = rem / 512, k = rem % 512;
    w2t[j] = f2bf(W2[l * 131072 + k * 256 + n]);
  }
}

// ---------- node input embedding (bf16 h0) ----------
__global__ __launch_bounds__(256) void k_node_init(
    const int* __restrict__ xa, const int* __restrict__ xc,
    const float* __restrict__ e1, const float* __restrict__ e2,
    u16* __restrict__ h, int N) {
  int idx = blockIdx.x * 256 + threadIdx.x;
  if (idx >= N * 64) return;
  int node = idx >> 6, c = (idx & 63) * 4;
  int a = xa[node], ch = xc[node];
  float4 v1 = *(const float4*)&e1[a * 256 + c];
  float4 v2 = *(const float4*)&e2[ch * 256 + c];
  ushort4v o;
  o[0] = f2bf(v1.x + v2.x); o[1] = f2bf(v1.y + v2.y);
  o[2] = f2bf(v1.z + v2.z); o[3] = f2bf(v1.w + v2.w);
  *(ushort4v*)&h[(size_t)node * 256 + c] = o;
}

// ---------- CSR build ----------
__global__ __launch_bounds__(256) void k_deg_count(
    const int* __restrict__ dst, int* __restrict__ deg, int E) {
  int e = blockIdx.x * 256 + threadIdx.x;
  if (e < E) atomicAdd(&deg[dst[e]], 1);
}

__global__ __launch_bounds__(256) void k_scan1(
    const int* __restrict__ deg, int* __restrict__ rp,
    int* __restrict__ bsum, int N) {
  __shared__ int s[256];
  int i = blockIdx.x * 256 + threadIdx.x;
  int v = (i < N) ? deg[i] : 0;
  s[threadIdx.x] = v;
  __syncthreads();
#pragma unroll
  for (int off = 1; off < 256; off <<= 1) {
    int t = (threadIdx.x >= off) ? s[threadIdx.x - off] : 0;
    __syncthreads();
    s[threadIdx.x] += t;
    __syncthreads();
  }
  if (i < N) rp[i] = s[threadIdx.x] - v;
  if (threadIdx.x == 255) bsum[blockIdx.x] = s[255];
}

__global__ __launch_bounds__(512) void k_scan2(
    const int* __restrict__ bsum, int* __restrict__ bexcl, int B) {
  __shared__ int s[512];
  int v = (threadIdx.x < B) ? bsum[threadIdx.x] : 0;
  s[threadIdx.x] = v;
  __syncthreads();
#pragma unroll
  for (int off = 1; off < 512; off <<= 1) {
    int t = (threadIdx.x >= off) ? s[threadIdx.x - off] : 0;
    __syncthreads();
    s[threadIdx.x] += t;
    __syncthreads();
  }
  if (threadIdx.x < B) bexcl[threadIdx.x] = s[threadIdx.x] - v;
}

__global__ __launch_bounds__(256) void k_scan3(
    int* __restrict__ rp, const int* __restrict__ bexcl,
    int* __restrict__ cur, int N, int E) {
  int i = blockIdx.x * 256 + threadIdx.x;
  if (i < N) {
    int v = rp[i] + bexcl[blockIdx.x];
    rp[i] = v;
    cur[i] = v;
  }
  if (i == 0) rp[N] = E;
}

__global__ __launch_bounds__(256) void k_fill(
    const int* __restrict__ src, const int* __restrict__ dst,
    const int* __restrict__ et, const int* __restrict__ ed,
    int* __restrict__ cur, u32* __restrict__ adj, int E) {
  int e = blockIdx.x * 256 + threadIdx.x;
  if (e >= E) return;
  int pos = atomicAdd(&cur[dst[e]], 1);
  adj[pos] = (u32)src[e] | ((u32)et[e] << 17) | ((u32)ed[e] << 20);
}

// ---------- gather-aggregate: reads bf16 normalized h, no BN inside --------
__global__ __launch_bounds__(256) void k_gather(
    const u16* __restrict__ h, const int* __restrict__ rp,
    const u32* __restrict__ adj, const float* __restrict__ ee1,
    const float* __restrict__ ee2, u16* __restrict__ aggb, int N) {
  int node = blockIdx.x * 4 + (threadIdx.x >> 6);
  if (node >= N) return;
  int lane = threadIdx.x & 63;
  int c = lane * 4;
  float4 a0 = b2f4(*(const ushort4v*)&h[(size_t)node * 256 + c]);
  float4 a1 = make_float4(0.f, 0.f, 0.f, 0.f);
  float4 a2 = a1, a3 = a1;
  u32 tcA = 0, tcB = 0;
  int beg = rp[node], end = rp[node + 1];
  int i = beg;
  for (; i + 4 <= end; i += 4) {
    u32 p0 = adj[i], p1 = adj[i + 1], p2 = adj[i + 2], p3 = adj[i + 3];
    float4 v0 = b2f4(*(const ushort4v*)&h[(size_t)(p0 & 0x1FFFF) * 256 + c]);
    float4 v1 = b2f4(*(const ushort4v*)&h[(size_t)(p1 & 0x1FFFF) * 256 + c]);
    float4 v2 = b2f4(*(const ushort4v*)&h[(size_t)(p2 & 0x1FFFF) * 256 + c]);
    float4 v3 = b2f4(*(const ushort4v*)&h[(size_t)(p3 & 0x1FFFF) * 256 + c]);
    a0.x += v0.x; a0.y += v0.y; a0.z += v0.z; a0.w += v0.w;
    a1.x += v1.x; a1.y += v1.y; a1.z += v1.z; a1.w += v1.w;
    a2.x += v2.x; a2.y += v2.y; a2.z += v2.z; a2.w += v2.w;
    a3.x += v3.x; a3.y += v3.y; a3.z += v3.z; a3.w += v3.w;
#pragma unroll
    for (int u = 0; u < 4; ++u) {
      u32 p = (u == 0) ? p0 : (u == 1) ? p1 : (u == 2) ? p2 : p3;
      u32 t = (p >> 17) & 7, r = (p >> 20) & 3;
      tcA += (t < 4) ? (1u << (t * 8)) : 0u;
      tcB += ((t == 4) ? 1u : 0u) + ((r == 0) ? 256u : 0u) +
             ((r == 1) ? 65536u : 0u);
    }
  }
  for (; i < end; ++i) {
    u32 p = adj[i];
    float4 v = b2f4(*(const ushort4v*)&h[(size_t)(p & 0x1FFFF) * 256 + c]);
    a0.x += v.x; a0.y += v.y; a0.z += v.z; a0.w += v.w;
    u32 t = (p >> 17) & 7, r = (p >> 20) & 3;
    tcA += (t < 4) ? (1u << (t * 8)) : 0u;
    tcB += ((t == 4) ? 1u : 0u) + ((r == 0) ? 256u : 0u) +
           ((r == 1) ? 65536u : 0u);
  }
  int deg = end - beg;
  int i0 = tcA & 255, i1 = (tcA >> 8) & 255, i2 = (tcA >> 16) & 255,
      i3 = (tcA >> 24) & 255;
  int i4 = (int)(tcB & 255) + 1;
  int r0 = (int)((tcB >> 8) & 255) + 1;
  int r1 = (int)((tcB >> 16) & 255);
  int i5 = deg - i0 - i1 - i2 - i3 - (i4 - 1);
  int r2 = deg - (r0 - 1) - r1;
  float ct[6], cr[3];
  ct[0] = (float)i0; ct[1] = (float)i1; ct[2] = (float)i2;
  ct[3] = (float)i3; ct[4] = (float)i4; ct[5] = (float)i5;
  cr[0] = (float)r0; cr[1] = (float)r1; cr[2] = (float)r2;

  float ax = a0.x + a1.x + a2.x + a3.x;
  float ay = a0.y + a1.y + a2.y + a3.y;
  float az = a0.z + a1.z + a2.z + a3.z;
  float aw = a0.w + a1.w + a2.w + a3.w;
#pragma unroll
  for (int t = 0; t < 6; ++t) {
    float4 e = *(const float4*)&ee1[t * 256 + c];
    ax += ct[t] * e.x; ay += ct[t] * e.y;
    az += ct[t] * e.z; aw += ct[t] * e.w;
  }
#pragma unroll
  for (int r = 0; r < 3; ++r) {
    float4 e = *(const float4*)&ee2[r * 256 + c];
    ax += cr[r] * e.x; ay += cr[r] * e.y;
    az += cr[r] * e.z; aw += cr[r] * e.w;
  }
  ushort4v o;
  o[0] = f2bf(ax); o[1] = f2bf(ay); o[2] = f2bf(az); o[3] = f2bf(aw);
  *(ushort4v*)&aggb[(size_t)node * 256 + c] = o;
}

// ---------- MFMA GEMM: 128x256 tile, 8 waves (2x4), BK=32, XOR-swizzled LDS,
// 2-phase double-buffer with counted vmcnt(3).
// OUTMODE: 0 = f32, 2 = bf16+relu.
template <int K, int NC, int OUTMODE, bool STATS>
__global__ __launch_bounds__(512) void k_gemm(
    const u16* __restrict__ A, const u16* __restrict__ Bt,
    const float* __restrict__ bias, void* __restrict__ outp,
    float* __restrict__ st, int M) {
  constexpr int NSTEP = K / 32;
  __shared__ u16 As[2][128 * 32];
  __shared__ u16 Bs[2][256 * 32];
  const int tid = threadIdx.x;
  const int lane = tid & 63;
  const int wv = tid >> 6;               // 0..7
  const int wrow = wv >> 2, wcol = wv & 3;
  const int m0 = blockIdx.x * 128;
  const int n0 = blockIdx.y * 256;
  const int fr = lane & 15;
  const int kgb = (lane >> 4) * 16;      // fragment k-offset in bytes
  const int swz = (fr & 3) << 4;

  f32x4 acc[4][4];
#pragma unroll
  for (int m = 0; m < 4; ++m)
#pragma unroll
    for (int n = 0; n < 4; ++n) acc[m][n] = (f32x4){0.f, 0.f, 0.f, 0.f};

  auto stage = [&](int k0, int b) {
    {
      const int cidx = tid;
      int row = cidx >> 2, q = (cidx & 3) ^ (row & 3);
      int ar = m0 + row;
      if (ar >= M) ar = M - 1;
      gload_lds16(A + (size_t)ar * K + k0 + q * 8,
                  (char*)As[b] + (tid & ~63) * 16);
    }
#pragma unroll
    for (int j = 0; j < 2; ++j) {
      const int cidx = j * 512 + tid;
      int row = cidx >> 2, q = (cidx & 3) ^ (row & 3);
      gload_lds16(Bt + (size_t)(n0 + row) * K + k0 + q * 8,
                  (char*)Bs[b] + (j * 512 + (tid & ~63)) * 16);
    }
  };

  stage(0, 0);
  for (int ks = 0; ks < NSTEP; ++ks) {
    const int b = ks & 1;
    if (ks + 1 < NSTEP) {
      stage((ks + 1) * 32, b ^ 1);
      asm volatile("s_waitcnt vmcnt(3)" ::: "memory");
    } else {
      asm volatile("s_waitcnt vmcnt(0)" ::: "memory");
    }
    __builtin_amdgcn_sched_barrier(0);
    __builtin_amdgcn_s_barrier();
    __builtin_amdgcn_sched_barrier(0);
    bf16x8 af[4], bf[4];
#pragma unroll
    for (int m = 0; m < 4; ++m)
      af[m] = *(const bf16x8*)((const char*)As[b] +
                               (wrow * 64 + m * 16 + fr) * 64 + (kgb ^ swz));
#pragma unroll
    for (int n = 0; n < 4; ++n)
      bf[n] = *(const bf16x8*)((const char*)Bs[b] +
                               (wcol * 64 + n * 16 + fr) * 64 + (kgb ^ swz));
#pragma unroll
    for (int m = 0; m < 4; ++m)
#pragma unroll
      for (int n = 0; n < 4; ++n)
        acc[m][n] = __builtin_amdgcn_mfma_f32_16x16x32_bf16(af[m], bf[n],
                                                            acc[m][n], 0, 0, 0);
    __builtin_amdgcn_sched_barrier(0);
    __builtin_amdgcn_s_barrier();
  }

  float* sst = (float*)As;  // 512 floats: [0..255]=sum, [256..511]=sumsq
  if (STATS) {
    __syncthreads();
    sst[tid] = 0.f;
    __syncthreads();
  }

  const int rb = (lane >> 4) * 4;
  float s[4], s2[4];
#pragma unroll
  for (int n = 0; n < 4; ++n) { s[n] = 0.f; s2[n] = 0.f; }
#pragma unroll
  for (int m = 0; m < 4; ++m) {
#pragma unroll
    for (int n = 0; n < 4; ++n) {
      const int col = n0 + wcol * 64 + n * 16 + fr;
      const float bv = bias[col];
#pragma unroll
      for (int j = 0; j < 4; ++j) {
        const int row = m0 + wrow * 64 + m * 16 + rb + j;
        if (row < M) {
          float v = acc[m][n][j] + bv;
          if (OUTMODE == 2) {
            v = fmaxf(v, 0.f);
            ((u16*)outp)[(size_t)row * NC + col] = f2bf(v);
          } else {
            ((float*)outp)[(size_t)row * NC + col] = v;
          }
          if (STATS) {
            s[n] += v;
            s2[n] += v * v;
          }
        }
      }
    }
  }
  if (STATS) {
#pragma unroll
    for (int n = 0; n < 4; ++n) {
      s[n] += __shfl_xor(s[n], 16);
      s[n] += __shfl_xor(s[n], 32);
      s2[n] += __shfl_xor(s2[n], 16);
      s2[n] += __shfl_xor(s2[n], 32);
    }
    if (lane < 16) {
#pragma unroll
      for (int n = 0; n < 4; ++n) {
        const int col = wcol * 64 + n * 16 + fr;  // n0 == 0 when STATS
        atomicAdd(&sst[col], s[n]);
        atomicAdd(&sst[256 + col], s2[n]);
      }
    }
    __syncthreads();
    unsafeAtomicAdd(&st[tid], sst[tid]);
  }
}

__global__ __launch_bounds__(256) void k_bn_finalize(
    float* __restrict__ stats, const float* __restrict__ gamma,
    const float* __restrict__ beta, int l, float invN) {
  int c = threadIdx.x;
  float mean = stats[c] * invN;
  float var = stats[256 + c] * invN - mean * mean;
  float sc = gamma[l * 256 + c] * rsqrtf(var + 1e-5f);
  stats[512 + c] = sc;
  stats[768 + c] = beta[l * 256 + c] - mean * sc;
}

// ---------- BN apply: f32 hl -> normalized output.
// BF16RELU=true: relu + bf16 (next layer's h). false: f32 (final output).
template <bool BF16RELU>
__global__ __launch_bounds__(256) void k_bn_apply(
    const float* __restrict__ hl, const float* __restrict__ stats,
    void* __restrict__ out, int N) {
  int idx = blockIdx.x * 256 + threadIdx.x;
  if (idx >= N * 64) return;
  int c = (idx & 63) * 4;
  float4 v = *(const float4*)&hl[(size_t)idx * 4];
  float4 sc = *(const float4*)&stats[512 + c];
  float4 sh = *(const float4*)&stats[768 + c];
  float4 o = make_float4(v.x * sc.x + sh.x, v.y * sc.y + sh.y,
                         v.z * sc.z + sh.z, v.w * sc.w + sh.w);
  if (BF16RELU) {
    ushort4v ob;
    ob[0] = f2bf(fmaxf(o.x, 0.f)); ob[1] = f2bf(fmaxf(o.y, 0.f));
    ob[2] = f2bf(fmaxf(o.z, 0.f)); ob[3] = f2bf(fmaxf(o.w, 0.f));
    *(ushort4v*)&((u16*)out)[(size_t)idx * 4] = ob;
  } else {
    *(float4*)&((float*)out)[(size_t)idx * 4] = o;
  }
}

// ---------- launch ----------
extern "C" void kernel_launch(void* const* d_in, const int* in_sizes, int n_in,
                              void* d_out, int out_size, void* d_ws,
                              size_t ws_size, hipStream_t stream) {
  const int* x_atom = (const int*)d_in[0];
  const int* x_chir = (const int*)d_in[1];
  const int* esrc = (const int*)d_in[2];
  const int* edst = (const int*)d_in[3];
  const int* etype = (const int*)d_in[4];
  const int* edir = (const int*)d_in[5];
  const float* x_emb1 = (const float*)d_in[6];
  const float* x_emb2 = (const float*)d_in[7];
  const float* eemb1 = (const float*)d_in[8];
  const float* eemb2 = (const float*)d_in[9];
  const float* W1 = (const float*)d_in[10];
  const float* b1 = (const float*)d_in[11];
  const float* W2 = (const float*)d_in[12];
  const float* b2 = (const float*)d_in[13];
  const float* gamma = (const float*)d_in[14];
  const float* beta = (const float*)d_in[15];

  const int N = in_sizes[0];
  const int E = in_sizes[2];

  char* ws = (char*)d_ws;
  size_t off = 0;
  char* bufA = ws + off; off += (size_t)N * 1024;  // hn (bf16) / interb
  char* bufB = ws + off; off += (size_t)N * 1024;  // hl (f32)
  u16* aggb = (u16*)(ws + off); off += (size_t)N * 256 * 2;
  u16* w1t = (u16*)(ws + off); off += (size_t)5 * 512 * 256 * 2;
  u16* w2t = (u16*)(ws + off); off += (size_t)5 * 256 * 512 * 2;
  int* rp = (int*)(ws + off); off += (size_t)(N + 1) * 4;
  int* degcur = (int*)(ws + off); off += (size_t)N * 4;
  int* bsum = (int*)(ws + off); off += 512 * 4;
  int* bexcl = (int*)(ws + off); off += 512 * 4;
  u32* adj = (u32*)(ws + off); off += (size_t)E * 4;
  float* statsAll = (float*)(ws + off); off += 5 * 1024 * 4;  // per-layer

  const int gN64 = (N * 64 + 255) / 256;
  const int gE = (E + 255) / 256;
  const int B1 = (N + 255) / 256;
  const int NB128 = (N + 127) / 128;  // 782

  u16* hn = (u16*)bufA;        // normalized bf16 h (input of each layer)
  u16* interb = (u16*)bufA;    // GEMM1 out, aliases hn (dead after gather)
  float* hl = (float*)bufB;    // raw GEMM2 out (f32)

  // --- one-time: CSR build + weight cast + node embed + stats zero ---
  hipMemsetAsync(degcur, 0, (size_t)N * 4, stream);
  hipMemsetAsync(statsAll, 0, 5 * 1024 * 4, stream);
  k_deg_count<<<gE, 256, 0, stream>>>(edst, degcur, E);
  k_scan1<<<B1, 256, 0, stream>>>(degcur, rp, bsum, N);
  k_scan2<<<1, 512, 0, stream>>>(bsum, bexcl, B1);
  k_scan3<<<B1, 256, 0, stream>>>(rp, bexcl, degcur, N, E);
  k_fill<<<gE, 256, 0, stream>>>(esrc, edst, etype, edir, degcur, adj, E);
  k_cast_weights<<<(2 * 5 * 512 * 256 + 255) / 256, 256, 0, stream>>>(W1, W2,
                                                                      w1t, w2t);
  k_node_init<<<gN64, 256, 0, stream>>>(x_atom, x_chir, x_emb1, x_emb2, hn, N);

  for (int l = 0; l < 5; ++l) {
    const float* ee1 = eemb1 + (size_t)l * 6 * 256;
    const float* ee2 = eemb2 + (size_t)l * 3 * 256;
    float* st = statsAll + l * 1024;

    k_gather<<<(N + 3) / 4, 256, 0, stream>>>(hn, rp, adj, ee1, ee2, aggb, N);
    k_gemm<256, 512, 2, false><<<dim3(NB128, 2), 512, 0, stream>>>(
        aggb, w1t + (size_t)l * 512 * 256, b1 + l * 512, interb, nullptr, N);
    k_gemm<512, 256, 0, true><<<dim3(NB128, 1), 512, 0, stream>>>(
        interb, w2t + (size_t)l * 256 * 512, b2 + l * 256, hl, st, N);
    k_bn_finalize<<<1, 256, 0, stream>>>(st, gamma, beta, l, 1.f / N);
    if (l < 4)
      k_bn_apply<true><<<gN64, 256, 0, stream>>>(hl, st, hn, N);
    else
      k_bn_apply<false><<<gN64, 256, 0, stream>>>(hl, st, d_out, N);
  }
}